// Round 1
// 1856.277 us; speedup vs baseline: 1.5452x; 1.5452x over previous
//
#include <hip/hip_runtime.h>
#include <math.h>

// PCA_75307956568420: 128 x (64x64 symmetric eigenproblem) whose eigenvector
// SIGNS must match LAPACK ssyevd on the f32 gram. Full SSTEDC replication:
// Householder tridiag (dsytd2 'L') -> dstedc scale -> dlaed0 splits (16x4) ->
// DSTEQR base solves (QL/QR, dlartg/dlaev2 conventions) -> dlaed1/2/3 merges
// WITH faithful dlaed2 deflation -> back-transform. f32-rounding at every
// level boundary keeps decision comparisons within ~1ulp of the reference.
//
// R1 perf changes (decision paths byte-identical):
//  - DSTEQR: cooperative 16-lane-per-block (redundant uniform scalar code,
//    row-parallel rotation apply) instead of 4 serial lanes.
//  - Secular solver: shared rho*z^2, 1 divide per pole per iter (reciprocal
//    reuse), convergence at 1e-12 relative (results are f32-rounded; 1e-12
//    is 4 orders below f32 lsb of the stored deltas).
//  - gram: 512 threads, float4 global loads both passes, f64-staged tile,
//    double-buffered load/compute pipeline (T14 split).

#define NMAT 128
#define EPS32 5.9604644775390625e-8
#define SAFMIN32 1.1754943508222875e-38

static __device__ __forceinline__ double f32r(double x) { return (double)(float)x; }
static __device__ __forceinline__ double lapsign(double a, double b) {
  return (b >= 0.0) ? fabs(a) : -fabs(a);
}

__device__ __forceinline__ double wred_sum(double v) {
#pragma unroll
  for (int o = 32; o > 0; o >>= 1) v += __shfl_xor(v, o, 64);
  return v;
}
__device__ __forceinline__ double wred_max(double v) {
#pragma unroll
  for (int o = 32; o > 0; o >>= 1) v = fmax(v, __shfl_xor(v, o, 64));
  return v;
}

// ------- Kernel 1: column stats + normalized Gram (f64 acc, f32 out) -------
__global__ __launch_bounds__(512) void gram_kernel(const float* __restrict__ x,
                                                   float* __restrict__ gbuf) {
  const int bh = blockIdx.x, b = bh >> 4, h = bh & 15;
  const float* base = x + (size_t)b * 4096 * 1024 + h * 64;
  __shared__ double rs1[32][64];
  __shared__ double rs2[32][64];
  __shared__ int rsc[32][64];
  __shared__ float sm[64], si[64];
  __shared__ double tiled[2][64][68];
  const int tid = threadIdx.x, q = tid & 15, r0 = tid >> 4, lane = tid & 63;

  // ---- pass 1: column stats, float4 loads ----
  double s1[4] = {0.0, 0.0, 0.0, 0.0}, s2[4] = {0.0, 0.0, 0.0, 0.0};
  int cc[4] = {0, 0, 0, 0};
#pragma unroll 4
  for (int s = r0; s < 4096; s += 32) {
    const float4 v = *(const float4*)&base[(size_t)s * 1024 + 4 * q];
    const float vs[4] = {v.x, v.y, v.z, v.w};
#pragma unroll
    for (int k = 0; k < 4; ++k) {
      const double dv = (double)vs[k];
      s1[k] += dv;
      s2[k] += dv * dv;
      cc[k] += (vs[k] != 0.0f) ? 1 : 0;
    }
  }
#pragma unroll
  for (int k = 0; k < 4; ++k) {
    rs1[r0][4 * q + k] = s1[k];
    rs2[r0][4 * q + k] = s2[k];
    rsc[r0][4 * q + k] = cc[k];
  }
  __syncthreads();
  if (tid < 64) {
    double S1 = 0.0, S2 = 0.0;
    int C = 0;
    for (int a = 0; a < 32; ++a) { S1 += rs1[a][tid]; S2 += rs2[a][tid]; C += rsc[a][tid]; }
    const double m = (C > 0) ? S1 / (double)C : 0.0;
    double var = (C > 0) ? (S2 - 2.0 * m * S1 + 4096.0 * m * m) / (double)C : 0.0;
    var = fmax(var, 0.0);
    const double sd = sqrt(var);
    sm[tid] = (float)m;
    si[tid] = (sd > 0.0) ? (float)(1.0 / sd) : 0.0f;
  }
  __syncthreads();

  const float4 mj4 = *(const float4*)&sm[4 * q];
  const float4 iv4 = *(const float4*)&si[4 * q];

  // stash: normalize (f32 math identical to original) + row-nonzero mask,
  // store as f64 so the FMA loop has no cvt on the critical path.
  auto stash = [&](int buf, float4 v, int sl) {
    const bool nz4 = (v.x != 0.0f) || (v.y != 0.0f) || (v.z != 0.0f) || (v.w != 0.0f);
    const unsigned long long mb = __ballot(nz4);
    const unsigned rowm = (unsigned)(mb >> ((lane >> 4) << 4)) & 0xFFFFu;
    double* tr = &tiled[buf][sl][4 * q];
    if (rowm) {
      tr[0] = (double)((v.x - mj4.x) * iv4.x);
      tr[1] = (double)((v.y - mj4.y) * iv4.y);
      tr[2] = (double)((v.z - mj4.z) * iv4.z);
      tr[3] = (double)((v.w - mj4.w) * iv4.w);
    } else {
      tr[0] = 0.0; tr[1] = 0.0; tr[2] = 0.0; tr[3] = 0.0;
    }
  };

  double acc[2][4];
#pragma unroll
  for (int r = 0; r < 2; ++r)
#pragma unroll
    for (int c = 0; c < 4; ++c) acc[r][c] = 0.0;

  // prologue: tile 0
  {
    const float4 p0 = *(const float4*)&base[(size_t)(r0) * 1024 + 4 * q];
    const float4 p1 = *(const float4*)&base[(size_t)(r0 + 32) * 1024 + 4 * q];
    stash(0, p0, r0);
    stash(0, p1, r0 + 32);
  }
  __syncthreads();

  for (int t = 0; t < 64; ++t) {
    const int cur = t & 1;
    float4 n0, n1;
    const bool more = (t + 1 < 64);
    if (more) {  // issue next-tile loads early; latency hides under FMA
      const size_t sb = (size_t)(t + 1) * 64;
      n0 = *(const float4*)&base[(sb + r0) * 1024 + 4 * q];
      n1 = *(const float4*)&base[(sb + r0 + 32) * 1024 + 4 * q];
    }
    for (int ss = 0; ss < 64; ++ss) {
      const double a0 = tiled[cur][ss][2 * r0];
      const double a1 = tiled[cur][ss][2 * r0 + 1];
      const double* bp = &tiled[cur][ss][4 * q];
      const double b0 = bp[0], b1 = bp[1], b2 = bp[2], b3 = bp[3];
      acc[0][0] += a0 * b0; acc[0][1] += a0 * b1; acc[0][2] += a0 * b2; acc[0][3] += a0 * b3;
      acc[1][0] += a1 * b0; acc[1][1] += a1 * b1; acc[1][2] += a1 * b2; acc[1][3] += a1 * b3;
    }
    if (more) {  // write into the OTHER buffer: disjoint from readers this iter
      stash(cur ^ 1, n0, r0);
      stash(cur ^ 1, n1, r0 + 32);
    }
    __syncthreads();
  }

  float* G = gbuf + (size_t)bh * 4096;
#pragma unroll
  for (int r = 0; r < 2; ++r)
#pragma unroll
    for (int c = 0; c < 4; ++c)
      G[(2 * r0 + r) * 64 + 4 * q + c] = (float)acc[r][c];
}

// ----------------------------- DLARTG / DLAEV2 -----------------------------
static __device__ void dlartg_d(double f, double g, double& cs, double& sn,
                                double& r) {
  if (g == 0.0) { cs = 1.0; sn = 0.0; r = f; }
  else if (f == 0.0) { cs = 0.0; sn = 1.0; r = g; }
  else {
    r = sqrt(f * f + g * g);
    cs = f / r; sn = g / r;
    if (fabs(f) > fabs(g) && cs < 0.0) { cs = -cs; sn = -sn; r = -r; }
  }
}

static __device__ void dlaev2_d(double a, double b, double c, double& rt1,
                                double& rt2, double& cs1, double& sn1) {
  double sm = a + c, df = a - c, adf = fabs(df), tb = b + b, ab = fabs(tb);
  double acmx, acmn;
  if (fabs(a) > fabs(c)) { acmx = a; acmn = c; } else { acmx = c; acmn = a; }
  double rt;
  if (adf > ab) rt = adf * sqrt(1.0 + (ab / adf) * (ab / adf));
  else if (adf < ab) rt = ab * sqrt(1.0 + (adf / ab) * (adf / ab));
  else rt = ab * sqrt(2.0);
  int sgn1;
  if (sm < 0.0) {
    rt1 = 0.5 * (sm - rt); sgn1 = -1;
    rt2 = (acmx / rt1) * acmn - (b / rt1) * b;
  } else if (sm > 0.0) {
    rt1 = 0.5 * (sm + rt); sgn1 = 1;
    rt2 = (acmx / rt1) * acmn - (b / rt1) * b;
  } else { rt1 = 0.5 * rt; rt2 = -0.5 * rt; sgn1 = 1; }
  int sgn2; double cs;
  if (df >= 0.0) { cs = df + rt; sgn2 = 1; } else { cs = df - rt; sgn2 = -1; }
  double acs = fabs(cs);
  if (acs > ab) {
    double ct = -tb / cs;
    sn1 = 1.0 / sqrt(1.0 + ct * ct); cs1 = ct * sn1;
  } else {
    if (ab == 0.0) { cs1 = 1.0; sn1 = 0.0; }
    else {
      double tn = -cs / tb;
      cs1 = 1.0 / sqrt(1.0 + tn * tn); sn1 = tn * cs1;
    }
  }
  if (sgn1 == sgn2) { double tn = cs1; cs1 = -sn1; sn1 = tn; }
}

// ------------------ DSTEQR (n=16, COMPZ='I'), cooperative -------------------
// All 16 lanes of a group execute the scalar recurrence redundantly (inputs
// uniform within the group -> identical results, benign same-value LDS
// writes); Z rotations / swaps are applied one row per lane.
static __device__ __forceinline__ void rot1(double (*Zs)[65], int base, int row,
                                            int k1, int k2, double c, double s) {
  double a = Zs[base + row][base + k1], b = Zs[base + row][base + k2];
  Zs[base + row][base + k1] = c * a + s * b;
  Zs[base + row][base + k2] = -s * a + c * b;
}

static __device__ void dsteqr16_coop(double* d, double* e, double (*Zs)[65],
                                     int base, int row, double* cw, double* sw) {
  const int n = 16, nm1 = 15;
  const double eps = EPS32, eps2 = EPS32 * EPS32;
  int l1 = 0, jtot = 0, nmaxit = n * 30;
  while (l1 < n) {
    if (l1 > 0) e[l1 - 1] = 0.0;
    int m;
    for (m = l1; m < nm1; ++m) {
      double tst = fabs(e[m]);
      if (tst == 0.0) break;
      if (tst <= (sqrt(fabs(d[m])) * sqrt(fabs(d[m + 1]))) * eps) {
        e[m] = 0.0; break;
      }
    }
    int l = l1, lend = m;
    l1 = m + 1;
    if (lend == l) continue;
    if (fabs(d[lend]) < fabs(d[l])) { int t = l; l = lend; lend = t; }
    if (lend > l) {  // ---- QL ----
      for (;;) {
        int mm;
        if (l != lend) {
          for (mm = l; mm < lend; ++mm) {
            double tst = e[mm] * e[mm];
            if (tst <= (eps2 * fabs(d[mm])) * fabs(d[mm + 1]) + SAFMIN32) break;
          }
        } else mm = lend;
        if (mm < lend) e[mm] = 0.0;
        double p = d[l];
        if (mm == l) { d[l] = p; ++l; if (l <= lend) continue; else break; }
        if (mm == l + 1) {
          double rt1, rt2, c, s;
          dlaev2_d(d[l], e[l], d[l + 1], rt1, rt2, c, s);
          rot1(Zs, base, row, l, l + 1, c, s);
          d[l] = rt1; d[l + 1] = rt2; e[l] = 0.0;
          l += 2; if (l <= lend) continue; else break;
        }
        if (jtot == nmaxit) break;
        ++jtot;
        double g = (d[l + 1] - p) / (2.0 * e[l]);
        double r = sqrt(g * g + 1.0);
        g = d[mm] - p + e[l] / (g + lapsign(r, g));
        double s = 1.0, c = 1.0; p = 0.0;
        for (int i = mm - 1; i >= l; --i) {
          double f = s * e[i], b = c * e[i];
          dlartg_d(g, f, c, s, r);
          if (i != mm - 1) e[i + 1] = r;
          g = d[i + 1] - p;
          r = (d[i] - g) * s + 2.0 * c * b;
          p = s * r;
          d[i + 1] = g + p;
          g = c * r - b;
          cw[i] = c; sw[i] = -s;
        }
        for (int k = mm - 1; k >= l; --k) rot1(Zs, base, row, k, k + 1, cw[k], sw[k]);
        d[l] -= p; e[l] = g;
      }
    } else {  // ---- QR ----
      for (;;) {
        int mm;
        if (l != lend) {
          for (mm = l; mm > lend; --mm) {
            double tst = e[mm - 1] * e[mm - 1];
            if (tst <= (eps2 * fabs(d[mm])) * fabs(d[mm - 1]) + SAFMIN32) break;
          }
        } else mm = lend;
        if (mm > lend) e[mm - 1] = 0.0;
        double p = d[l];
        if (mm == l) { d[l] = p; --l; if (l >= lend) continue; else break; }
        if (mm == l - 1) {
          double rt1, rt2, c, s;
          dlaev2_d(d[l - 1], e[l - 1], d[l], rt1, rt2, c, s);
          rot1(Zs, base, row, l - 1, l, c, s);
          d[l - 1] = rt1; d[l] = rt2; e[l - 1] = 0.0;
          l -= 2; if (l >= lend) continue; else break;
        }
        if (jtot == nmaxit) break;
        ++jtot;
        double g = (d[l - 1] - p) / (2.0 * e[l - 1]);
        double r = sqrt(g * g + 1.0);
        g = d[mm] - p + e[l - 1] / (g + lapsign(r, g));
        double s = 1.0, c = 1.0; p = 0.0;
        for (int i = mm; i <= l - 1; ++i) {
          double f = s * e[i], b = c * e[i];
          dlartg_d(g, f, c, s, r);
          if (i != mm) e[i - 1] = r;
          g = d[i] - p;
          r = (d[i + 1] - g) * s + 2.0 * c * b;
          p = s * r;
          d[i] = g + p;
          g = c * r - b;
          cw[i] = c; sw[i] = s;
        }
        for (int k = mm; k <= l - 1; ++k) rot1(Zs, base, row, k, k + 1, cw[k], sw[k]);
        d[l] -= p; e[l - 1] = g;
      }
    }
  }
  // final selection sort ascending, row-parallel column swaps
  for (int ii = 1; ii < n; ++ii) {
    int i = ii - 1, k = i; double p = d[i];
    for (int j = ii; j < n; ++j)
      if (d[j] < p) { k = j; p = d[j]; }
    if (k != i) {
      d[k] = d[i]; d[i] = p;
      double t = Zs[base + row][base + i];
      Zs[base + row][base + i] = Zs[base + row][base + k];
      Zs[base + row][base + k] = t;
    }
  }
}

// ------------- D&C merge with faithful DLAED2 deflation (dlaed1/2/3) -------
static __device__ void merge_dc(int off, int n, double rho_in, int lane,
                                double (*Zs)[65], double (*Zn)[65], float* ScF,
                                double* dd, double* dlam, double* wz,
                                double* zt, double* lamv, double* zloc,
                                double* dloc, double* lamfin, double* dvalS,
                                double* rz2, int* indx, int* slist, int* dlist,
                                int* dcolS) {
  const int N1 = n / 2;
  if (lane < n) {
    int r = (lane < N1) ? (off + N1 - 1) : (off + N1);
    double z = Zs[r][off + lane];
    if (rho_in < 0.0 && lane >= N1) z = -z;
    zloc[lane] = z * 0.70710678118654752440;
    dloc[lane] = dd[off + lane];
  }
  __syncthreads();
  const double rho = fabs(2.0 * rho_in);
  // stable DLAMRG merge order
  if (lane < n) {
    double a = dloc[lane];
    int pos;
    if (lane < N1) {
      int c2 = 0;
      for (int i = N1; i < n; ++i) c2 += (dloc[i] < a) ? 1 : 0;
      pos = lane + c2;
    } else {
      int c1 = 0;
      for (int i = 0; i < N1; ++i) c1 += (dloc[i] <= a) ? 1 : 0;
      pos = (lane - N1) + c1;
    }
    indx[pos] = lane;
  }
  __syncthreads();
  double mx = (lane < n) ? fmax(fabs(dloc[lane]), fabs(zloc[lane])) : 0.0;
  mx = wred_max(mx);
  const double tol = 8.0 * EPS32 * mx;
  __syncthreads();

  // ---- DLAED2 deflation scan (wave-uniform; rotations row-parallel) ----
  int K = 0, nD = 0;
  {
    int pj = -1, j = 0;
    for (; j < n; ++j) {
      int cj = indx[j];
      if (rho * fabs(zloc[cj]) <= tol) { dlist[nD] = cj; ++nD; }
      else { pj = cj; ++j; break; }
    }
    if (pj >= 0) {
      for (; j < n; ++j) {
        int nj = indx[j];
        if (rho * fabs(zloc[nj]) <= tol) { dlist[nD] = nj; ++nD; continue; }
        double s0 = zloc[pj], c0 = zloc[nj];
        double ta = sqrt(c0 * c0 + s0 * s0);  // DLAPY2 (values O(1))
        double tt = dloc[nj] - dloc[pj];
        double cc = c0 / ta, ss = -s0 / ta;
        if (fabs(tt * cc * ss) <= tol) {
          // type-2 deflation: DROT(Q(:,pj), Q(:,nj), cc, ss)
          zloc[nj] = ta; zloc[pj] = 0.0;
          {
            double a = Zs[lane][off + pj], b = Zs[lane][off + nj];
            Zs[lane][off + pj] = cc * a + ss * b;
            Zs[lane][off + nj] = cc * b - ss * a;
          }
          double ndp = dloc[pj] * cc * cc + dloc[nj] * ss * ss;
          dloc[nj] = dloc[pj] * ss * ss + dloc[nj] * cc * cc;
          dloc[pj] = ndp;
          dlist[nD] = pj; ++nD;
          pj = nj;
        } else {
          slist[K] = pj; ++K;
          pj = nj;
        }
      }
      slist[K] = pj; ++K;
    }
  }
  __syncthreads();
  // sort deflated by (updated) d ascending (stable)
  if (lane == 0) {
    for (int m = 0; m < nD; ++m) { dvalS[m] = dloc[dlist[m]]; dcolS[m] = dlist[m]; }
    for (int a = 1; a < nD; ++a) {
      double v = dvalS[a]; int ci = dcolS[a]; int b = a - 1;
      while (b >= 0 && dvalS[b] > v) { dvalS[b+1] = dvalS[b]; dcolS[b+1] = dcolS[b]; --b; }
      dvalS[b+1] = v; dcolS[b+1] = ci;
    }
  }
  __syncthreads();
  if (lane < K) {
    const double dv = dloc[slist[lane]], zv = zloc[slist[lane]];
    dlam[lane] = dv; wz[lane] = zv; rz2[lane] = rho * (zv * zv);
  }
  __syncthreads();

  // ---- secular roots (dlaed4-style, tau relative to nearest pole) ----
  if (lane < K) {
    int jl = lane, pjp; double lo, hi;
    double sumz2 = 0.0;
    for (int i = 0; i < K; ++i) sumz2 += wz[i] * wz[i];
    if (jl < K - 1) {
      double mid = 0.5 * (dlam[jl] + dlam[jl + 1]);
      double f = 1.0;
      for (int i = 0; i < K; ++i) f += rho * wz[i] * wz[i] / (dlam[i] - mid);
      double gaph = 0.5 * (dlam[jl + 1] - dlam[jl]);
      if (f > 0.0) { pjp = jl;     lo = 0.0;   hi = gaph; }
      else         { pjp = jl + 1; lo = -gaph; hi = 0.0;  }
    } else { pjp = K - 1; lo = 0.0; hi = rho * sumz2; }
    double sig = dlam[pjp];
    double tau = 0.5 * (lo + hi);
    for (int it = 0; it < 100; ++it) {
      double g = 1.0, gp = 0.0;
      for (int i = 0; i < K; ++i) {
        double inv = 1.0 / ((dlam[i] - sig) - tau);
        double q = rz2[i] * inv;
        g += q;
        gp += q * inv;
      }
      if (g > 0.0) hi = tau; else lo = tau;
      double tn = tau - g / gp;
      if (!(tn > lo && tn < hi)) tn = 0.5 * (lo + hi);
      double df = fabs(tn - tau);
      tau = tn;
      if (df <= 1.0e-12 * (fabs(tau) + 1e-30)) break;
    }
    lamv[jl] = sig + tau;
    for (int i = 0; i < K; ++i)
      ScF[i * 65 + jl] = (float)((dlam[i] - sig) - tau);
  }
  __syncthreads();
  // ---- dlaed3 z-tilde: sign(ztilde)=sign(w) ----
  if (lane < K) {
    int i = lane;
    double wv = (double)ScF[i * 65 + i];
    for (int j2 = 0; j2 < K; ++j2) {
      if (j2 == i) continue;
      wv *= (double)ScF[i * 65 + j2] / (dlam[i] - dlam[j2]);
    }
    double mag = sqrt(fmax(-wv, 0.0));
    zt[i] = (wz[i] >= 0.0) ? mag : -mag;
  }
  __syncthreads();
  // ---- secular vectors (normalized positively) ----
  if (lane < K) {
    double nrm2 = 0.0;
    for (int i = 0; i < K; ++i) {
      double sv = zt[i] / (double)ScF[i * 65 + lane];
      ScF[i * 65 + lane] = (float)sv;
      nrm2 += sv * sv;
    }
    float inv = (float)(1.0 / sqrt(nrm2));
    for (int i = 0; i < K; ++i) ScF[i * 65 + lane] *= inv;
  }
  __syncthreads();
  // ---- build new columns into Zn at final (merged ascending) positions ----
  if (lane < K) {
    int cnt = 0;
    for (int m = 0; m < nD; ++m) cnt += (dvalS[m] < lamv[lane]) ? 1 : 0;
    int fp = lane + cnt;
    for (int c0 = 0; c0 < n; c0 += 16) {
      double res[16];
#pragma unroll
      for (int t = 0; t < 16; ++t) res[t] = 0.0;
      for (int i = 0; i < K; ++i) {
        double sv = (double)ScF[i * 65 + lane];
        int col = off + slist[i];
#pragma unroll
        for (int t = 0; t < 16; ++t) res[t] += Zs[off + c0 + t][col] * sv;
      }
#pragma unroll
      for (int t = 0; t < 16; ++t) Zn[c0 + t][fp] = res[t];
    }
    lamfin[fp] = lamv[lane];
  }
  __syncthreads();
  for (int m = 0; m < nD; ++m) {
    int cnt = 0;
    for (int jl = 0; jl < K; ++jl) cnt += (lamv[jl] <= dvalS[m]) ? 1 : 0;
    int fp = m + cnt;
    if (lane < n) Zn[lane][fp] = Zs[off + lane][off + dcolS[m]];
    if (lane == 0) lamfin[fp] = dvalS[m];
  }
  __syncthreads();
  if (lane < n) {
    for (int c = 0; c < n; ++c) Zs[off + lane][off + c] = Zn[lane][c];
    dd[off + lane] = f32r(lamfin[lane]);  // f32 level boundary
  }
  __syncthreads();
}

// ---------------- Kernel 2: eigensolver + oracle + output ------------------
__global__ __launch_bounds__(64, 1) void eig_kernel(float* __restrict__ gbuf) {
  const int bh = blockIdx.x, b = bh >> 4, h = bh & 15;
  const int lane = threadIdx.x;
  float* G = gbuf + (size_t)bh * 4096;

  __shared__ double Zs[64][65];
  __shared__ double Zn[64][65];
  __shared__ double varch[64][64];
  __shared__ double ScD[2080];
  __shared__ double dd[64], ee[64], tauv[64], varr[64], wv[64];
  __shared__ double dlam[64], wz[64], zt[64], lamv[64], zloc[64], dloc[64];
  __shared__ double lamfin[64], dvalS[64], dsave[64], esave[64], rz2[64];
  __shared__ double cwA[4][16], swA[4][16];
  __shared__ int indx[64], slist[64], dlist[64], dcolS[64];
  float* ScF = (float*)ScD;

  // ---- load gram into LDS (f64) ----
  double (*Zw)[65] = Zs;
  for (int r = 0; r < 64; ++r) Zw[r][lane] = (double)G[r * 64 + lane];
  __syncthreads();

  // ---- Householder tridiagonalization (dsytd2, UPLO='L') ----
  for (int i = 0; i < 63; ++i) {
    double xv = (lane >= i + 2) ? Zw[i][lane] : 0.0;
    double xn2 = wred_sum(xv * xv);
    double alpha = Zw[i][i + 1];
    double beta, taui;
    if (xn2 == 0.0) { taui = 0.0; beta = alpha; }
    else {
      double nrm = sqrt(alpha * alpha + xn2);
      beta = (alpha >= 0.0) ? -nrm : nrm;
      taui = (beta - alpha) / beta;
    }
    if (lane == 0) { dd[i] = Zw[i][i]; ee[i] = beta; tauv[i] = taui; }
    if (taui != 0.0) {
      double vl = (lane == i + 1) ? 1.0
                                  : ((lane >= i + 2) ? xv / (alpha - beta) : 0.0);
      varr[lane] = vl;
      if (lane >= i + 1) varch[i][lane] = vl;
      __syncthreads();
      double wr = 0.0;
      for (int c = i + 1; c < 64; ++c) wr += Zw[c][lane] * varr[c];
      wr *= taui;
      double wtv = wred_sum((lane >= i + 1) ? wr * vl : 0.0);
      wr -= 0.5 * taui * wtv * vl;
      wv[lane] = (lane >= i + 1) ? wr : 0.0;
      __syncthreads();
      if (lane >= i + 1) {
        double vc = vl, wc = wr;
        for (int r = i + 1; r < 64; ++r)
          Zw[r][lane] -= (varr[r] * wc + wv[r] * vc);
      }
      __syncthreads();
    } else {
      __syncthreads();
    }
  }
  if (lane == 0) dd[63] = Zw[63][63];
  __syncthreads();

  // ---- emulate f32 ssytrd output, sstedc scaling, dlaed0 corrections ----
  dd[lane] = f32r(dd[lane]);
  if (lane < 63) ee[lane] = f32r(ee[lane]);
  __syncthreads();
  double mx = fabs(dd[lane]);
  if (lane < 63) mx = fmax(mx, fabs(ee[lane]));
  const double orgnrm = wred_max(mx);
  dd[lane] = f32r(dd[lane] / orgnrm);
  if (lane < 63) ee[lane] = f32r(ee[lane] / orgnrm);
  __syncthreads();
  dsave[lane] = dd[lane];
  esave[lane] = (lane < 63) ? ee[lane] : 0.0;
  __syncthreads();
  if (lane == 0) {
    const int ms[3] = {15, 31, 47};
    for (int a = 0; a < 3; ++a) {
      double ae = fabs(ee[ms[a]]);
      dd[ms[a]] = f32r(dd[ms[a]] - ae);
      dd[ms[a] + 1] = f32r(dd[ms[a] + 1] - ae);
    }
  }
  __syncthreads();

  // ---- base solves: DSTEQR on 4 x 16 blocks, 16 cooperative lanes each ----
  for (int r = 0; r < 64; ++r) Zs[r][lane] = (r == lane) ? 1.0 : 0.0;
  __syncthreads();
  {
    const int bb = lane >> 4, row = lane & 15;
    dsteqr16_coop(dd + bb * 16, ee + bb * 16, Zs, bb * 16, row, cwA[bb], swA[bb]);
  }
  __syncthreads();
  dd[lane] = f32r(dd[lane]);  // f32 level boundary
  __syncthreads();

  // ---- merges: (16+16)A, (16+16)B, then 32+32 ----
  merge_dc(0, 32, ee[15], lane, Zs, Zn, ScF, dd, dlam, wz, zt, lamv, zloc,
           dloc, lamfin, dvalS, rz2, indx, slist, dlist, dcolS);
  merge_dc(32, 32, ee[47], lane, Zs, Zn, ScF, dd, dlam, wz, zt, lamv, zloc,
           dloc, lamfin, dvalS, rz2, indx, slist, dlist, dcolS);
  merge_dc(0, 64, ee[31], lane, Zs, Zn, ScF, dd, dlam, wz, zt, lamv, zloc,
           dloc, lamfin, dvalS, rz2, indx, slist, dlist, dcolS);

  // ---- ORACLE: ||T Z - Z L||oo on the scaled tridiagonal ----
  double tres = 0.0;
  {
    const double lam = dd[lane];
    for (int i = 0; i < 64; ++i) {
      double tv = dsave[i] * Zs[i][lane];
      if (i > 0) tv += esave[i - 1] * Zs[i - 1][lane];
      if (i < 63) tv += esave[i] * Zs[i + 1][lane];
      tres = fmax(tres, fabs(tv - lam * Zs[i][lane]));
    }
  }
  tres = wred_max(tres);
  const bool dc_bad = !(tres <= 2e-5);  // NaN-safe; f32-accurate pipeline

  // ---- back-transform: Z <- H(0) ... H(62) Z ----
  for (int i = 62; i >= 0; --i) {
    double ti = tauv[i];
    if (ti != 0.0) {
      varr[lane] = varch[i][lane];
      __syncthreads();
      double wc = 0.0;
      for (int r = i + 1; r < 64; ++r) wc += varr[r] * Zs[r][lane];
      wc *= ti;
      for (int r = i + 1; r < 64; ++r) Zs[r][lane] -= varr[r] * wc;
      __syncthreads();
    }
  }
  __syncthreads();

  const double sentinel = dc_bad ? 1.0e6 : 0.0;
  // ---- output: out[b, h*64+i, j] = w_j * V[j][i] / 8 ----
  const double wj = dd[lane] * orgnrm * 0.125;
  for (int i2 = 0; i2 < 64; ++i2) {
    G[i2 * 64 + lane] = (float)(wj * Zs[lane][i2] + sentinel);
  }
}

extern "C" void kernel_launch(void* const* d_in, const int* in_sizes, int n_in,
                              void* d_out, int out_size, void* d_ws,
                              size_t ws_size, hipStream_t stream) {
  (void)in_sizes; (void)n_in; (void)out_size; (void)d_ws; (void)ws_size;
  const float* x = (const float*)d_in[0];
  float* out = (float*)d_out;
  gram_kernel<<<dim3(NMAT), dim3(512), 0, stream>>>(x, out);
  eig_kernel<<<dim3(NMAT), dim3(64), 0, stream>>>(out);
}

// Round 4
// 1759.183 us; speedup vs baseline: 1.6305x; 1.0552x over previous
//
#include <hip/hip_runtime.h>
#include <math.h>

// PCA_75307956568420: 128 x (64x64 symmetric eigenproblem) whose eigenvector
// SIGNS must match LAPACK ssyevd on the f32 gram. Full SSTEDC replication:
// Householder tridiag (dsytd2 'L') -> dstedc scale -> dlaed0 splits (16x4) ->
// DSTEQR base solves (QL/QR, dlartg/dlaev2 conventions) -> dlaed1/2/3 merges
// WITH faithful dlaed2 deflation -> back-transform. f32-rounding at every
// level boundary keeps decision comparisons within ~1ulp of the reference.
//
// R4 = BISECT round. R2/R3 failed with bit-identical absmax (deterministic
// logic bug somewhere in the R2 eig rewrite; two audits inconclusive).
// This round: eig_kernel reverted to the R1 source VERBATIM (known-pass),
// gram_kernel kept at the R2 version (256 thr, 4x4 f64 acc, double-buffered
// pipeline). Outcome isolates the bug to eig-rewrite vs gram.

#define NMAT 128
#define EPS32 5.9604644775390625e-8
#define SAFMIN32 1.1754943508222875e-38

static __device__ __forceinline__ double f32r(double x) { return (double)(float)x; }
static __device__ __forceinline__ double lapsign(double a, double b) {
  return (b >= 0.0) ? fabs(a) : -fabs(a);
}

__device__ __forceinline__ double wred_sum(double v) {
#pragma unroll
  for (int o = 32; o > 0; o >>= 1) v += __shfl_xor(v, o, 64);
  return v;
}
__device__ __forceinline__ double wred_max(double v) {
#pragma unroll
  for (int o = 32; o > 0; o >>= 1) v = fmax(v, __shfl_xor(v, o, 64));
  return v;
}

// ------- Kernel 1: column stats + normalized Gram (f64 acc, f32 out) -------
// (R2 version: 256 threads, 4x4 acc/thread, float4 loads, dbuf pipeline.)
__global__ __launch_bounds__(256) void gram_kernel(const float* __restrict__ x,
                                                   float* __restrict__ gbuf) {
  const int bh = blockIdx.x, b = bh >> 4, h = bh & 15;
  const float* base = x + (size_t)b * 4096 * 1024 + h * 64;
  __shared__ double rs1[16][64];
  __shared__ double rs2[16][64];
  __shared__ int rsc[16][64];
  __shared__ float sm[64], si[64];
  __shared__ double tiled[2][64][68];
  const int tid = threadIdx.x, q = tid & 15, r0 = tid >> 4, lane = tid & 63;

  // ---- pass 1: column stats, float4 loads ----
  double s1[4] = {0.0, 0.0, 0.0, 0.0}, s2[4] = {0.0, 0.0, 0.0, 0.0};
  int cc[4] = {0, 0, 0, 0};
#pragma unroll 4
  for (int s = r0; s < 4096; s += 16) {
    const float4 v = *(const float4*)&base[(size_t)s * 1024 + 4 * q];
    const float vs[4] = {v.x, v.y, v.z, v.w};
#pragma unroll
    for (int k = 0; k < 4; ++k) {
      const double dv = (double)vs[k];
      s1[k] += dv;
      s2[k] += dv * dv;
      cc[k] += (vs[k] != 0.0f) ? 1 : 0;
    }
  }
#pragma unroll
  for (int k = 0; k < 4; ++k) {
    rs1[r0][4 * q + k] = s1[k];
    rs2[r0][4 * q + k] = s2[k];
    rsc[r0][4 * q + k] = cc[k];
  }
  __syncthreads();
  if (tid < 64) {
    double S1 = 0.0, S2 = 0.0;
    int C = 0;
    for (int a = 0; a < 16; ++a) { S1 += rs1[a][tid]; S2 += rs2[a][tid]; C += rsc[a][tid]; }
    const double m = (C > 0) ? S1 / (double)C : 0.0;
    double var = (C > 0) ? (S2 - 2.0 * m * S1 + 4096.0 * m * m) / (double)C : 0.0;
    var = fmax(var, 0.0);
    const double sd = sqrt(var);
    sm[tid] = (float)m;
    si[tid] = (sd > 0.0) ? (float)(1.0 / sd) : 0.0f;
  }
  __syncthreads();

  const float4 mj4 = *(const float4*)&sm[4 * q];
  const float4 iv4 = *(const float4*)&si[4 * q];

  auto stash = [&](int buf, const float4& v, int sl) {
    const bool nz4 = (v.x != 0.0f) || (v.y != 0.0f) || (v.z != 0.0f) || (v.w != 0.0f);
    const unsigned long long mb = __ballot(nz4);
    const unsigned rowm = (unsigned)(mb >> (lane & 48)) & 0xFFFFu;
    double* tr = &tiled[buf][sl][4 * q];
    if (rowm) {
      tr[0] = (double)((v.x - mj4.x) * iv4.x);
      tr[1] = (double)((v.y - mj4.y) * iv4.y);
      tr[2] = (double)((v.z - mj4.z) * iv4.z);
      tr[3] = (double)((v.w - mj4.w) * iv4.w);
    } else {
      tr[0] = 0.0; tr[1] = 0.0; tr[2] = 0.0; tr[3] = 0.0;
    }
  };

  double acc[4][4];
#pragma unroll
  for (int r = 0; r < 4; ++r)
#pragma unroll
    for (int c = 0; c < 4; ++c) acc[r][c] = 0.0;

  // prologue: tile 0 (rows r0, r0+16, r0+32, r0+48)
  {
    const float4 p0 = *(const float4*)&base[(size_t)(r0) * 1024 + 4 * q];
    const float4 p1 = *(const float4*)&base[(size_t)(r0 + 16) * 1024 + 4 * q];
    const float4 p2 = *(const float4*)&base[(size_t)(r0 + 32) * 1024 + 4 * q];
    const float4 p3 = *(const float4*)&base[(size_t)(r0 + 48) * 1024 + 4 * q];
    stash(0, p0, r0); stash(0, p1, r0 + 16); stash(0, p2, r0 + 32); stash(0, p3, r0 + 48);
  }
  __syncthreads();

  for (int t = 0; t < 64; ++t) {
    const int cur = t & 1;
    float4 n0, n1, n2, n3;
    const bool more = (t + 1 < 64);
    if (more) {
      const size_t sb = (size_t)(t + 1) * 64;
      n0 = *(const float4*)&base[(sb + r0) * 1024 + 4 * q];
      n1 = *(const float4*)&base[(sb + r0 + 16) * 1024 + 4 * q];
      n2 = *(const float4*)&base[(sb + r0 + 32) * 1024 + 4 * q];
      n3 = *(const float4*)&base[(sb + r0 + 48) * 1024 + 4 * q];
    }
    for (int ss = 0; ss < 64; ++ss) {
      const double* ta = &tiled[cur][ss][4 * r0];
      const double* tb = &tiled[cur][ss][4 * q];
      const double a0 = ta[0], a1 = ta[1], a2 = ta[2], a3 = ta[3];
      const double b0 = tb[0], b1 = tb[1], b2 = tb[2], b3 = tb[3];
      acc[0][0] += a0 * b0; acc[0][1] += a0 * b1; acc[0][2] += a0 * b2; acc[0][3] += a0 * b3;
      acc[1][0] += a1 * b0; acc[1][1] += a1 * b1; acc[1][2] += a1 * b2; acc[1][3] += a1 * b3;
      acc[2][0] += a2 * b0; acc[2][1] += a2 * b1; acc[2][2] += a2 * b2; acc[2][3] += a2 * b3;
      acc[3][0] += a3 * b0; acc[3][1] += a3 * b1; acc[3][2] += a3 * b2; acc[3][3] += a3 * b3;
    }
    if (more) {
      stash(cur ^ 1, n0, r0); stash(cur ^ 1, n1, r0 + 16);
      stash(cur ^ 1, n2, r0 + 32); stash(cur ^ 1, n3, r0 + 48);
    }
    __syncthreads();
  }

  float* G = gbuf + (size_t)bh * 4096;
#pragma unroll
  for (int r = 0; r < 4; ++r)
#pragma unroll
    for (int c = 0; c < 4; ++c)
      G[(4 * r0 + r) * 64 + 4 * q + c] = (float)acc[r][c];
}

// ----------------------------- DLARTG / DLAEV2 -----------------------------
static __device__ void dlartg_d(double f, double g, double& cs, double& sn,
                                double& r) {
  if (g == 0.0) { cs = 1.0; sn = 0.0; r = f; }
  else if (f == 0.0) { cs = 0.0; sn = 1.0; r = g; }
  else {
    r = sqrt(f * f + g * g);
    cs = f / r; sn = g / r;
    if (fabs(f) > fabs(g) && cs < 0.0) { cs = -cs; sn = -sn; r = -r; }
  }
}

static __device__ void dlaev2_d(double a, double b, double c, double& rt1,
                                double& rt2, double& cs1, double& sn1) {
  double sm = a + c, df = a - c, adf = fabs(df), tb = b + b, ab = fabs(tb);
  double acmx, acmn;
  if (fabs(a) > fabs(c)) { acmx = a; acmn = c; } else { acmx = c; acmn = a; }
  double rt;
  if (adf > ab) rt = adf * sqrt(1.0 + (ab / adf) * (ab / adf));
  else if (adf < ab) rt = ab * sqrt(1.0 + (adf / ab) * (adf / ab));
  else rt = ab * sqrt(2.0);
  int sgn1;
  if (sm < 0.0) {
    rt1 = 0.5 * (sm - rt); sgn1 = -1;
    rt2 = (acmx / rt1) * acmn - (b / rt1) * b;
  } else if (sm > 0.0) {
    rt1 = 0.5 * (sm + rt); sgn1 = 1;
    rt2 = (acmx / rt1) * acmn - (b / rt1) * b;
  } else { rt1 = 0.5 * rt; rt2 = -0.5 * rt; sgn1 = 1; }
  int sgn2; double cs;
  if (df >= 0.0) { cs = df + rt; sgn2 = 1; } else { cs = df - rt; sgn2 = -1; }
  double acs = fabs(cs);
  if (acs > ab) {
    double ct = -tb / cs;
    sn1 = 1.0 / sqrt(1.0 + ct * ct); cs1 = ct * sn1;
  } else {
    if (ab == 0.0) { cs1 = 1.0; sn1 = 0.0; }
    else {
      double tn = -cs / tb;
      cs1 = 1.0 / sqrt(1.0 + tn * tn); sn1 = tn * cs1;
    }
  }
  if (sgn1 == sgn2) { double tn = cs1; cs1 = -sn1; sn1 = tn; }
}

// ------------------ DSTEQR (n=16, COMPZ='I'), cooperative -------------------
// (R1 version, verbatim.) All 16 lanes of a group execute the scalar
// recurrence redundantly; Z rotations / swaps applied one row per lane.
static __device__ __forceinline__ void rot1(double (*Zs)[65], int base, int row,
                                            int k1, int k2, double c, double s) {
  double a = Zs[base + row][base + k1], b = Zs[base + row][base + k2];
  Zs[base + row][base + k1] = c * a + s * b;
  Zs[base + row][base + k2] = -s * a + c * b;
}

static __device__ void dsteqr16_coop(double* d, double* e, double (*Zs)[65],
                                     int base, int row, double* cw, double* sw) {
  const int n = 16, nm1 = 15;
  const double eps = EPS32, eps2 = EPS32 * EPS32;
  int l1 = 0, jtot = 0, nmaxit = n * 30;
  while (l1 < n) {
    if (l1 > 0) e[l1 - 1] = 0.0;
    int m;
    for (m = l1; m < nm1; ++m) {
      double tst = fabs(e[m]);
      if (tst == 0.0) break;
      if (tst <= (sqrt(fabs(d[m])) * sqrt(fabs(d[m + 1]))) * eps) {
        e[m] = 0.0; break;
      }
    }
    int l = l1, lend = m;
    l1 = m + 1;
    if (lend == l) continue;
    if (fabs(d[lend]) < fabs(d[l])) { int t = l; l = lend; lend = t; }
    if (lend > l) {  // ---- QL ----
      for (;;) {
        int mm;
        if (l != lend) {
          for (mm = l; mm < lend; ++mm) {
            double tst = e[mm] * e[mm];
            if (tst <= (eps2 * fabs(d[mm])) * fabs(d[mm + 1]) + SAFMIN32) break;
          }
        } else mm = lend;
        if (mm < lend) e[mm] = 0.0;
        double p = d[l];
        if (mm == l) { d[l] = p; ++l; if (l <= lend) continue; else break; }
        if (mm == l + 1) {
          double rt1, rt2, c, s;
          dlaev2_d(d[l], e[l], d[l + 1], rt1, rt2, c, s);
          rot1(Zs, base, row, l, l + 1, c, s);
          d[l] = rt1; d[l + 1] = rt2; e[l] = 0.0;
          l += 2; if (l <= lend) continue; else break;
        }
        if (jtot == nmaxit) break;
        ++jtot;
        double g = (d[l + 1] - p) / (2.0 * e[l]);
        double r = sqrt(g * g + 1.0);
        g = d[mm] - p + e[l] / (g + lapsign(r, g));
        double s = 1.0, c = 1.0; p = 0.0;
        for (int i = mm - 1; i >= l; --i) {
          double f = s * e[i], b = c * e[i];
          dlartg_d(g, f, c, s, r);
          if (i != mm - 1) e[i + 1] = r;
          g = d[i + 1] - p;
          r = (d[i] - g) * s + 2.0 * c * b;
          p = s * r;
          d[i + 1] = g + p;
          g = c * r - b;
          cw[i] = c; sw[i] = -s;
        }
        for (int k = mm - 1; k >= l; --k) rot1(Zs, base, row, k, k + 1, cw[k], sw[k]);
        d[l] -= p; e[l] = g;
      }
    } else {  // ---- QR ----
      for (;;) {
        int mm;
        if (l != lend) {
          for (mm = l; mm > lend; --mm) {
            double tst = e[mm - 1] * e[mm - 1];
            if (tst <= (eps2 * fabs(d[mm])) * fabs(d[mm - 1]) + SAFMIN32) break;
          }
        } else mm = lend;
        if (mm > lend) e[mm - 1] = 0.0;
        double p = d[l];
        if (mm == l) { d[l] = p; --l; if (l >= lend) continue; else break; }
        if (mm == l - 1) {
          double rt1, rt2, c, s;
          dlaev2_d(d[l - 1], e[l - 1], d[l], rt1, rt2, c, s);
          rot1(Zs, base, row, l - 1, l, c, s);
          d[l - 1] = rt1; d[l] = rt2; e[l - 1] = 0.0;
          l -= 2; if (l >= lend) continue; else break;
        }
        if (jtot == nmaxit) break;
        ++jtot;
        double g = (d[l - 1] - p) / (2.0 * e[l - 1]);
        double r = sqrt(g * g + 1.0);
        g = d[mm] - p + e[l - 1] / (g + lapsign(r, g));
        double s = 1.0, c = 1.0; p = 0.0;
        for (int i = mm; i <= l - 1; ++i) {
          double f = s * e[i], b = c * e[i];
          dlartg_d(g, f, c, s, r);
          if (i != mm) e[i - 1] = r;
          g = d[i] - p;
          r = (d[i + 1] - g) * s + 2.0 * c * b;
          p = s * r;
          d[i] = g + p;
          g = c * r - b;
          cw[i] = c; sw[i] = s;
        }
        for (int k = mm; k <= l - 1; ++k) rot1(Zs, base, row, k, k + 1, cw[k], sw[k]);
        d[l] -= p; e[l - 1] = g;
      }
    }
  }
  // final selection sort ascending, row-parallel column swaps
  for (int ii = 1; ii < n; ++ii) {
    int i = ii - 1, k = i; double p = d[i];
    for (int j = ii; j < n; ++j)
      if (d[j] < p) { k = j; p = d[j]; }
    if (k != i) {
      d[k] = d[i]; d[i] = p;
      double t = Zs[base + row][base + i];
      Zs[base + row][base + i] = Zs[base + row][base + k];
      Zs[base + row][base + k] = t;
    }
  }
}

// ------------- D&C merge with faithful DLAED2 deflation (dlaed1/2/3) -------
// (R1 version, verbatim.)
static __device__ void merge_dc(int off, int n, double rho_in, int lane,
                                double (*Zs)[65], double (*Zn)[65], float* ScF,
                                double* dd, double* dlam, double* wz,
                                double* zt, double* lamv, double* zloc,
                                double* dloc, double* lamfin, double* dvalS,
                                double* rz2, int* indx, int* slist, int* dlist,
                                int* dcolS) {
  const int N1 = n / 2;
  if (lane < n) {
    int r = (lane < N1) ? (off + N1 - 1) : (off + N1);
    double z = Zs[r][off + lane];
    if (rho_in < 0.0 && lane >= N1) z = -z;
    zloc[lane] = z * 0.70710678118654752440;
    dloc[lane] = dd[off + lane];
  }
  __syncthreads();
  const double rho = fabs(2.0 * rho_in);
  // stable DLAMRG merge order
  if (lane < n) {
    double a = dloc[lane];
    int pos;
    if (lane < N1) {
      int c2 = 0;
      for (int i = N1; i < n; ++i) c2 += (dloc[i] < a) ? 1 : 0;
      pos = lane + c2;
    } else {
      int c1 = 0;
      for (int i = 0; i < N1; ++i) c1 += (dloc[i] <= a) ? 1 : 0;
      pos = (lane - N1) + c1;
    }
    indx[pos] = lane;
  }
  __syncthreads();
  double mx = (lane < n) ? fmax(fabs(dloc[lane]), fabs(zloc[lane])) : 0.0;
  mx = wred_max(mx);
  const double tol = 8.0 * EPS32 * mx;
  __syncthreads();

  // ---- DLAED2 deflation scan (wave-uniform; rotations row-parallel) ----
  int K = 0, nD = 0;
  {
    int pj = -1, j = 0;
    for (; j < n; ++j) {
      int cj = indx[j];
      if (rho * fabs(zloc[cj]) <= tol) { dlist[nD] = cj; ++nD; }
      else { pj = cj; ++j; break; }
    }
    if (pj >= 0) {
      for (; j < n; ++j) {
        int nj = indx[j];
        if (rho * fabs(zloc[nj]) <= tol) { dlist[nD] = nj; ++nD; continue; }
        double s0 = zloc[pj], c0 = zloc[nj];
        double ta = sqrt(c0 * c0 + s0 * s0);  // DLAPY2 (values O(1))
        double tt = dloc[nj] - dloc[pj];
        double cc = c0 / ta, ss = -s0 / ta;
        if (fabs(tt * cc * ss) <= tol) {
          // type-2 deflation: DROT(Q(:,pj), Q(:,nj), cc, ss)
          zloc[nj] = ta; zloc[pj] = 0.0;
          {
            double a = Zs[lane][off + pj], b = Zs[lane][off + nj];
            Zs[lane][off + pj] = cc * a + ss * b;
            Zs[lane][off + nj] = cc * b - ss * a;
          }
          double ndp = dloc[pj] * cc * cc + dloc[nj] * ss * ss;
          dloc[nj] = dloc[pj] * ss * ss + dloc[nj] * cc * cc;
          dloc[pj] = ndp;
          dlist[nD] = pj; ++nD;
          pj = nj;
        } else {
          slist[K] = pj; ++K;
          pj = nj;
        }
      }
      slist[K] = pj; ++K;
    }
  }
  __syncthreads();
  // sort deflated by (updated) d ascending (stable)
  if (lane == 0) {
    for (int m = 0; m < nD; ++m) { dvalS[m] = dloc[dlist[m]]; dcolS[m] = dlist[m]; }
    for (int a = 1; a < nD; ++a) {
      double v = dvalS[a]; int ci = dcolS[a]; int b = a - 1;
      while (b >= 0 && dvalS[b] > v) { dvalS[b+1] = dvalS[b]; dcolS[b+1] = dcolS[b]; --b; }
      dvalS[b+1] = v; dcolS[b+1] = ci;
    }
  }
  __syncthreads();
  if (lane < K) {
    const double dv = dloc[slist[lane]], zv = zloc[slist[lane]];
    dlam[lane] = dv; wz[lane] = zv; rz2[lane] = rho * (zv * zv);
  }
  __syncthreads();

  // ---- secular roots (dlaed4-style, tau relative to nearest pole) ----
  if (lane < K) {
    int jl = lane, pjp; double lo, hi;
    double sumz2 = 0.0;
    for (int i = 0; i < K; ++i) sumz2 += wz[i] * wz[i];
    if (jl < K - 1) {
      double mid = 0.5 * (dlam[jl] + dlam[jl + 1]);
      double f = 1.0;
      for (int i = 0; i < K; ++i) f += rho * wz[i] * wz[i] / (dlam[i] - mid);
      double gaph = 0.5 * (dlam[jl + 1] - dlam[jl]);
      if (f > 0.0) { pjp = jl;     lo = 0.0;   hi = gaph; }
      else         { pjp = jl + 1; lo = -gaph; hi = 0.0;  }
    } else { pjp = K - 1; lo = 0.0; hi = rho * sumz2; }
    double sig = dlam[pjp];
    double tau = 0.5 * (lo + hi);
    for (int it = 0; it < 100; ++it) {
      double g = 1.0, gp = 0.0;
      for (int i = 0; i < K; ++i) {
        double inv = 1.0 / ((dlam[i] - sig) - tau);
        double q = rz2[i] * inv;
        g += q;
        gp += q * inv;
      }
      if (g > 0.0) hi = tau; else lo = tau;
      double tn = tau - g / gp;
      if (!(tn > lo && tn < hi)) tn = 0.5 * (lo + hi);
      double df = fabs(tn - tau);
      tau = tn;
      if (df <= 1.0e-12 * (fabs(tau) + 1e-30)) break;
    }
    lamv[jl] = sig + tau;
    for (int i = 0; i < K; ++i)
      ScF[i * 65 + jl] = (float)((dlam[i] - sig) - tau);
  }
  __syncthreads();
  // ---- dlaed3 z-tilde: sign(ztilde)=sign(w) ----
  if (lane < K) {
    int i = lane;
    double wv = (double)ScF[i * 65 + i];
    for (int j2 = 0; j2 < K; ++j2) {
      if (j2 == i) continue;
      wv *= (double)ScF[i * 65 + j2] / (dlam[i] - dlam[j2]);
    }
    double mag = sqrt(fmax(-wv, 0.0));
    zt[i] = (wz[i] >= 0.0) ? mag : -mag;
  }
  __syncthreads();
  // ---- secular vectors (normalized positively) ----
  if (lane < K) {
    double nrm2 = 0.0;
    for (int i = 0; i < K; ++i) {
      double sv = zt[i] / (double)ScF[i * 65 + lane];
      ScF[i * 65 + lane] = (float)sv;
      nrm2 += sv * sv;
    }
    float inv = (float)(1.0 / sqrt(nrm2));
    for (int i = 0; i < K; ++i) ScF[i * 65 + lane] *= inv;
  }
  __syncthreads();
  // ---- build new columns into Zn at final (merged ascending) positions ----
  if (lane < K) {
    int cnt = 0;
    for (int m = 0; m < nD; ++m) cnt += (dvalS[m] < lamv[lane]) ? 1 : 0;
    int fp = lane + cnt;
    for (int c0 = 0; c0 < n; c0 += 16) {
      double res[16];
#pragma unroll
      for (int t = 0; t < 16; ++t) res[t] = 0.0;
      for (int i = 0; i < K; ++i) {
        double sv = (double)ScF[i * 65 + lane];
        int col = off + slist[i];
#pragma unroll
        for (int t = 0; t < 16; ++t) res[t] += Zs[off + c0 + t][col] * sv;
      }
#pragma unroll
      for (int t = 0; t < 16; ++t) Zn[c0 + t][fp] = res[t];
    }
    lamfin[fp] = lamv[lane];
  }
  __syncthreads();
  for (int m = 0; m < nD; ++m) {
    int cnt = 0;
    for (int jl = 0; jl < K; ++jl) cnt += (lamv[jl] <= dvalS[m]) ? 1 : 0;
    int fp = m + cnt;
    if (lane < n) Zn[lane][fp] = Zs[off + lane][off + dcolS[m]];
    if (lane == 0) lamfin[fp] = dvalS[m];
  }
  __syncthreads();
  if (lane < n) {
    for (int c = 0; c < n; ++c) Zs[off + lane][off + c] = Zn[lane][c];
    dd[off + lane] = f32r(lamfin[lane]);  // f32 level boundary
  }
  __syncthreads();
}

// ---------------- Kernel 2: eigensolver + oracle + output ------------------
// (R1 version, verbatim: 64 threads, 1 wave.)
__global__ __launch_bounds__(64, 1) void eig_kernel(float* __restrict__ gbuf) {
  const int bh = blockIdx.x, b = bh >> 4, h = bh & 15;
  const int lane = threadIdx.x;
  float* G = gbuf + (size_t)bh * 4096;

  __shared__ double Zs[64][65];
  __shared__ double Zn[64][65];
  __shared__ double varch[64][64];
  __shared__ double ScD[2080];
  __shared__ double dd[64], ee[64], tauv[64], varr[64], wv[64];
  __shared__ double dlam[64], wz[64], zt[64], lamv[64], zloc[64], dloc[64];
  __shared__ double lamfin[64], dvalS[64], dsave[64], esave[64], rz2[64];
  __shared__ double cwA[4][16], swA[4][16];
  __shared__ int indx[64], slist[64], dlist[64], dcolS[64];
  float* ScF = (float*)ScD;

  // ---- load gram into LDS (f64) ----
  double (*Zw)[65] = Zs;
  for (int r = 0; r < 64; ++r) Zw[r][lane] = (double)G[r * 64 + lane];
  __syncthreads();

  // ---- Householder tridiagonalization (dsytd2, UPLO='L') ----
  for (int i = 0; i < 63; ++i) {
    double xv = (lane >= i + 2) ? Zw[i][lane] : 0.0;
    double xn2 = wred_sum(xv * xv);
    double alpha = Zw[i][i + 1];
    double beta, taui;
    if (xn2 == 0.0) { taui = 0.0; beta = alpha; }
    else {
      double nrm = sqrt(alpha * alpha + xn2);
      beta = (alpha >= 0.0) ? -nrm : nrm;
      taui = (beta - alpha) / beta;
    }
    if (lane == 0) { dd[i] = Zw[i][i]; ee[i] = beta; tauv[i] = taui; }
    if (taui != 0.0) {
      double vl = (lane == i + 1) ? 1.0
                                  : ((lane >= i + 2) ? xv / (alpha - beta) : 0.0);
      varr[lane] = vl;
      if (lane >= i + 1) varch[i][lane] = vl;
      __syncthreads();
      double wr = 0.0;
      for (int c = i + 1; c < 64; ++c) wr += Zw[c][lane] * varr[c];
      wr *= taui;
      double wtv = wred_sum((lane >= i + 1) ? wr * vl : 0.0);
      wr -= 0.5 * taui * wtv * vl;
      wv[lane] = (lane >= i + 1) ? wr : 0.0;
      __syncthreads();
      if (lane >= i + 1) {
        double vc = vl, wc = wr;
        for (int r = i + 1; r < 64; ++r)
          Zw[r][lane] -= (varr[r] * wc + wv[r] * vc);
      }
      __syncthreads();
    } else {
      __syncthreads();
    }
  }
  if (lane == 0) dd[63] = Zw[63][63];
  __syncthreads();

  // ---- emulate f32 ssytrd output, sstedc scaling, dlaed0 corrections ----
  dd[lane] = f32r(dd[lane]);
  if (lane < 63) ee[lane] = f32r(ee[lane]);
  __syncthreads();
  double mx = fabs(dd[lane]);
  if (lane < 63) mx = fmax(mx, fabs(ee[lane]));
  const double orgnrm = wred_max(mx);
  dd[lane] = f32r(dd[lane] / orgnrm);
  if (lane < 63) ee[lane] = f32r(ee[lane] / orgnrm);
  __syncthreads();
  dsave[lane] = dd[lane];
  esave[lane] = (lane < 63) ? ee[lane] : 0.0;
  __syncthreads();
  if (lane == 0) {
    const int ms[3] = {15, 31, 47};
    for (int a = 0; a < 3; ++a) {
      double ae = fabs(ee[ms[a]]);
      dd[ms[a]] = f32r(dd[ms[a]] - ae);
      dd[ms[a] + 1] = f32r(dd[ms[a] + 1] - ae);
    }
  }
  __syncthreads();

  // ---- base solves: DSTEQR on 4 x 16 blocks, 16 cooperative lanes each ----
  for (int r = 0; r < 64; ++r) Zs[r][lane] = (r == lane) ? 1.0 : 0.0;
  __syncthreads();
  {
    const int bb = lane >> 4, row = lane & 15;
    dsteqr16_coop(dd + bb * 16, ee + bb * 16, Zs, bb * 16, row, cwA[bb], swA[bb]);
  }
  __syncthreads();
  dd[lane] = f32r(dd[lane]);  // f32 level boundary
  __syncthreads();

  // ---- merges: (16+16)A, (16+16)B, then 32+32 ----
  merge_dc(0, 32, ee[15], lane, Zs, Zn, ScF, dd, dlam, wz, zt, lamv, zloc,
           dloc, lamfin, dvalS, rz2, indx, slist, dlist, dcolS);
  merge_dc(32, 32, ee[47], lane, Zs, Zn, ScF, dd, dlam, wz, zt, lamv, zloc,
           dloc, lamfin, dvalS, rz2, indx, slist, dlist, dcolS);
  merge_dc(0, 64, ee[31], lane, Zs, Zn, ScF, dd, dlam, wz, zt, lamv, zloc,
           dloc, lamfin, dvalS, rz2, indx, slist, dlist, dcolS);

  // ---- ORACLE: ||T Z - Z L||oo on the scaled tridiagonal ----
  double tres = 0.0;
  {
    const double lam = dd[lane];
    for (int i = 0; i < 64; ++i) {
      double tv = dsave[i] * Zs[i][lane];
      if (i > 0) tv += esave[i - 1] * Zs[i - 1][lane];
      if (i < 63) tv += esave[i] * Zs[i + 1][lane];
      tres = fmax(tres, fabs(tv - lam * Zs[i][lane]));
    }
  }
  tres = wred_max(tres);
  const bool dc_bad = !(tres <= 2e-5);  // NaN-safe; f32-accurate pipeline

  // ---- back-transform: Z <- H(0) ... H(62) Z ----
  for (int i = 62; i >= 0; --i) {
    double ti = tauv[i];
    if (ti != 0.0) {
      varr[lane] = varch[i][lane];
      __syncthreads();
      double wc = 0.0;
      for (int r = i + 1; r < 64; ++r) wc += varr[r] * Zs[r][lane];
      wc *= ti;
      for (int r = i + 1; r < 64; ++r) Zs[r][lane] -= varr[r] * wc;
      __syncthreads();
    }
  }
  __syncthreads();

  const double sentinel = dc_bad ? 1.0e6 : 0.0;
  // ---- output: out[b, h*64+i, j] = w_j * V[j][i] / 8 ----
  const double wj = dd[lane] * orgnrm * 0.125;
  for (int i2 = 0; i2 < 64; ++i2) {
    G[i2 * 64 + lane] = (float)(wj * Zs[lane][i2] + sentinel);
  }
}

extern "C" void kernel_launch(void* const* d_in, const int* in_sizes, int n_in,
                              void* d_out, int out_size, void* d_ws,
                              size_t ws_size, hipStream_t stream) {
  (void)in_sizes; (void)n_in; (void)out_size; (void)d_ws; (void)ws_size;
  const float* x = (const float*)d_in[0];
  float* out = (float*)d_out;
  gram_kernel<<<dim3(NMAT), dim3(256), 0, stream>>>(x, out);
  eig_kernel<<<dim3(NMAT), dim3(64), 0, stream>>>(out);
}

// Round 5
// 1683.090 us; speedup vs baseline: 1.7042x; 1.0452x over previous
//
#include <hip/hip_runtime.h>
#include <math.h>

// PCA_75307956568420: 128 x (64x64 symmetric eigenproblem) whose eigenvector
// SIGNS must match LAPACK ssyevd on the f32 gram. Full SSTEDC replication:
// Householder tridiag (dsytd2 'L') -> dstedc scale -> dlaed0 splits (16x4) ->
// DSTEQR base solves (QL/QR, dlartg/dlaev2 conventions) -> dlaed1/2/3 merges
// WITH faithful dlaed2 deflation -> back-transform. f32-rounding at every
// level boundary keeps decision comparisons within ~1ulp of the reference.
//
// R5 = R4 (passing) + ONE component re-introduced: dsteqr16_grp.
//  - d/e in lane-distributed registers (lane k of each 16-lane group holds
//    element k); scalar recurrence reads via absolute-lane __shfl (gb+idx),
//    ballot bits extracted per group. No LDS on the serial chain.
//  - Rotations fused into the bulge sweep with a register carry; application
//    order identical to R1's store-then-apply (verified against rot2cols for
//    QL (c,-s) and QR (c,+s)).
//  - 4 groups still in ONE wave (divergent), but per-rotation cost drops
//    ~1300 -> ~400 cy (LDS 120cy -> shfl 15cy on the chain).
// All other code identical to R4 (merges/tridiag/bt/oracle = R1 verbatim,
// gram = R2 version).

#define NMAT 128
#define EPS32 5.9604644775390625e-8
#define SAFMIN32 1.1754943508222875e-38

static __device__ __forceinline__ double f32r(double x) { return (double)(float)x; }
static __device__ __forceinline__ double lapsign(double a, double b) {
  return (b >= 0.0) ? fabs(a) : -fabs(a);
}

__device__ __forceinline__ double wred_sum(double v) {
#pragma unroll
  for (int o = 32; o > 0; o >>= 1) v += __shfl_xor(v, o, 64);
  return v;
}
__device__ __forceinline__ double wred_max(double v) {
#pragma unroll
  for (int o = 32; o > 0; o >>= 1) v = fmax(v, __shfl_xor(v, o, 64));
  return v;
}

// ------- Kernel 1: column stats + normalized Gram (f64 acc, f32 out) -------
// (R2 version: 256 threads, 4x4 acc/thread, float4 loads, dbuf pipeline.)
__global__ __launch_bounds__(256) void gram_kernel(const float* __restrict__ x,
                                                   float* __restrict__ gbuf) {
  const int bh = blockIdx.x, b = bh >> 4, h = bh & 15;
  const float* base = x + (size_t)b * 4096 * 1024 + h * 64;
  __shared__ double rs1[16][64];
  __shared__ double rs2[16][64];
  __shared__ int rsc[16][64];
  __shared__ float sm[64], si[64];
  __shared__ double tiled[2][64][68];
  const int tid = threadIdx.x, q = tid & 15, r0 = tid >> 4, lane = tid & 63;

  // ---- pass 1: column stats, float4 loads ----
  double s1[4] = {0.0, 0.0, 0.0, 0.0}, s2[4] = {0.0, 0.0, 0.0, 0.0};
  int cc[4] = {0, 0, 0, 0};
#pragma unroll 4
  for (int s = r0; s < 4096; s += 16) {
    const float4 v = *(const float4*)&base[(size_t)s * 1024 + 4 * q];
    const float vs[4] = {v.x, v.y, v.z, v.w};
#pragma unroll
    for (int k = 0; k < 4; ++k) {
      const double dv = (double)vs[k];
      s1[k] += dv;
      s2[k] += dv * dv;
      cc[k] += (vs[k] != 0.0f) ? 1 : 0;
    }
  }
#pragma unroll
  for (int k = 0; k < 4; ++k) {
    rs1[r0][4 * q + k] = s1[k];
    rs2[r0][4 * q + k] = s2[k];
    rsc[r0][4 * q + k] = cc[k];
  }
  __syncthreads();
  if (tid < 64) {
    double S1 = 0.0, S2 = 0.0;
    int C = 0;
    for (int a = 0; a < 16; ++a) { S1 += rs1[a][tid]; S2 += rs2[a][tid]; C += rsc[a][tid]; }
    const double m = (C > 0) ? S1 / (double)C : 0.0;
    double var = (C > 0) ? (S2 - 2.0 * m * S1 + 4096.0 * m * m) / (double)C : 0.0;
    var = fmax(var, 0.0);
    const double sd = sqrt(var);
    sm[tid] = (float)m;
    si[tid] = (sd > 0.0) ? (float)(1.0 / sd) : 0.0f;
  }
  __syncthreads();

  const float4 mj4 = *(const float4*)&sm[4 * q];
  const float4 iv4 = *(const float4*)&si[4 * q];

  auto stash = [&](int buf, const float4& v, int sl) {
    const bool nz4 = (v.x != 0.0f) || (v.y != 0.0f) || (v.z != 0.0f) || (v.w != 0.0f);
    const unsigned long long mb = __ballot(nz4);
    const unsigned rowm = (unsigned)(mb >> (lane & 48)) & 0xFFFFu;
    double* tr = &tiled[buf][sl][4 * q];
    if (rowm) {
      tr[0] = (double)((v.x - mj4.x) * iv4.x);
      tr[1] = (double)((v.y - mj4.y) * iv4.y);
      tr[2] = (double)((v.z - mj4.z) * iv4.z);
      tr[3] = (double)((v.w - mj4.w) * iv4.w);
    } else {
      tr[0] = 0.0; tr[1] = 0.0; tr[2] = 0.0; tr[3] = 0.0;
    }
  };

  double acc[4][4];
#pragma unroll
  for (int r = 0; r < 4; ++r)
#pragma unroll
    for (int c = 0; c < 4; ++c) acc[r][c] = 0.0;

  // prologue: tile 0 (rows r0, r0+16, r0+32, r0+48)
  {
    const float4 p0 = *(const float4*)&base[(size_t)(r0) * 1024 + 4 * q];
    const float4 p1 = *(const float4*)&base[(size_t)(r0 + 16) * 1024 + 4 * q];
    const float4 p2 = *(const float4*)&base[(size_t)(r0 + 32) * 1024 + 4 * q];
    const float4 p3 = *(const float4*)&base[(size_t)(r0 + 48) * 1024 + 4 * q];
    stash(0, p0, r0); stash(0, p1, r0 + 16); stash(0, p2, r0 + 32); stash(0, p3, r0 + 48);
  }
  __syncthreads();

  for (int t = 0; t < 64; ++t) {
    const int cur = t & 1;
    float4 n0, n1, n2, n3;
    const bool more = (t + 1 < 64);
    if (more) {
      const size_t sb = (size_t)(t + 1) * 64;
      n0 = *(const float4*)&base[(sb + r0) * 1024 + 4 * q];
      n1 = *(const float4*)&base[(sb + r0 + 16) * 1024 + 4 * q];
      n2 = *(const float4*)&base[(sb + r0 + 32) * 1024 + 4 * q];
      n3 = *(const float4*)&base[(sb + r0 + 48) * 1024 + 4 * q];
    }
    for (int ss = 0; ss < 64; ++ss) {
      const double* ta = &tiled[cur][ss][4 * r0];
      const double* tb = &tiled[cur][ss][4 * q];
      const double a0 = ta[0], a1 = ta[1], a2 = ta[2], a3 = ta[3];
      const double b0 = tb[0], b1 = tb[1], b2 = tb[2], b3 = tb[3];
      acc[0][0] += a0 * b0; acc[0][1] += a0 * b1; acc[0][2] += a0 * b2; acc[0][3] += a0 * b3;
      acc[1][0] += a1 * b0; acc[1][1] += a1 * b1; acc[1][2] += a1 * b2; acc[1][3] += a1 * b3;
      acc[2][0] += a2 * b0; acc[2][1] += a2 * b1; acc[2][2] += a2 * b2; acc[2][3] += a2 * b3;
      acc[3][0] += a3 * b0; acc[3][1] += a3 * b1; acc[3][2] += a3 * b2; acc[3][3] += a3 * b3;
    }
    if (more) {
      stash(cur ^ 1, n0, r0); stash(cur ^ 1, n1, r0 + 16);
      stash(cur ^ 1, n2, r0 + 32); stash(cur ^ 1, n3, r0 + 48);
    }
    __syncthreads();
  }

  float* G = gbuf + (size_t)bh * 4096;
#pragma unroll
  for (int r = 0; r < 4; ++r)
#pragma unroll
    for (int c = 0; c < 4; ++c)
      G[(4 * r0 + r) * 64 + 4 * q + c] = (float)acc[r][c];
}

// ----------------------------- DLARTG / DLAEV2 -----------------------------
static __device__ void dlartg_d(double f, double g, double& cs, double& sn,
                                double& r) {
  if (g == 0.0) { cs = 1.0; sn = 0.0; r = f; }
  else if (f == 0.0) { cs = 0.0; sn = 1.0; r = g; }
  else {
    r = sqrt(f * f + g * g);
    cs = f / r; sn = g / r;
    if (fabs(f) > fabs(g) && cs < 0.0) { cs = -cs; sn = -sn; r = -r; }
  }
}

static __device__ void dlaev2_d(double a, double b, double c, double& rt1,
                                double& rt2, double& cs1, double& sn1) {
  double sm = a + c, df = a - c, adf = fabs(df), tb = b + b, ab = fabs(tb);
  double acmx, acmn;
  if (fabs(a) > fabs(c)) { acmx = a; acmn = c; } else { acmx = c; acmn = a; }
  double rt;
  if (adf > ab) rt = adf * sqrt(1.0 + (ab / adf) * (ab / adf));
  else if (adf < ab) rt = ab * sqrt(1.0 + (adf / ab) * (adf / ab));
  else rt = ab * sqrt(2.0);
  int sgn1;
  if (sm < 0.0) {
    rt1 = 0.5 * (sm - rt); sgn1 = -1;
    rt2 = (acmx / rt1) * acmn - (b / rt1) * b;
  } else if (sm > 0.0) {
    rt1 = 0.5 * (sm + rt); sgn1 = 1;
    rt2 = (acmx / rt1) * acmn - (b / rt1) * b;
  } else { rt1 = 0.5 * rt; rt2 = -0.5 * rt; sgn1 = 1; }
  int sgn2; double cs;
  if (df >= 0.0) { cs = df + rt; sgn2 = 1; } else { cs = df - rt; sgn2 = -1; }
  double acs = fabs(cs);
  if (acs > ab) {
    double ct = -tb / cs;
    sn1 = 1.0 / sqrt(1.0 + ct * ct); cs1 = ct * sn1;
  } else {
    if (ab == 0.0) { cs1 = 1.0; sn1 = 0.0; }
    else {
      double tn = -cs / tb;
      cs1 = 1.0 / sqrt(1.0 + tn * tn); sn1 = tn * cs1;
    }
  }
  if (sgn1 == sgn2) { double tn = cs1; cs1 = -sn1; sn1 = tn; }
}

// ------------- DSTEQR (n=16, COMPZ='I'), group-local registers -------------
// Each 16-lane group solves one block. Lane (gb+k) holds d[k], e[k] in
// registers; the uniform scalar recurrence reads via absolute-lane __shfl
// (gb+idx). Rotations fused into the sweep with a register carry (identical
// application order to the R1 store-then-apply). Each lane owns Z row
// base+row. Groups diverge from each other (exec-mask serialization), but
// the per-rotation chain cost drops ~1300 -> ~400 cy.
static __device__ void dsteqr16_grp(double (*Zs)[65], int base, int lane,
                                    double& dk, double& ek) {
  const int n = 16, nm1 = 15;
  const double eps = EPS32, eps2 = EPS32 * EPS32;
  const int gb = lane & 48;   // group base lane
  const int row = lane & 15;  // group-local index; also Z-row owner
  int l1 = 0, jtot = 0, nmaxit = n * 30;
  while (l1 < n) {
    if (l1 > 0) { if (row == l1 - 1) ek = 0.0; }
    int m;
    {
      double dkp1 = __shfl(dk, gb + ((row + 1) & 15));
      bool cond = (fabs(ek) <= (sqrt(fabs(dk)) * sqrt(fabs(dkp1))) * eps);
      unsigned grp = (unsigned)((__ballot(cond) >> gb) & 0xFFFFull);
      grp &= 0x7FFFu & ~((1u << l1) - 1);
      m = grp ? (__ffs(grp) - 1) : nm1;
      if (m < nm1) { if (row == m) ek = 0.0; }
    }
    int l = l1, lend = m;
    l1 = m + 1;
    if (lend == l) continue;
    if (fabs(__shfl(dk, gb + lend)) < fabs(__shfl(dk, gb + l))) {
      int t = l; l = lend; lend = t;
    }
    if (lend > l) {  // ---- QL ----
      for (;;) {
        int mm;
        {
          double dkp1 = __shfl(dk, gb + ((row + 1) & 15));
          bool cond = (ek * ek <= (eps2 * fabs(dk)) * fabs(dkp1) + SAFMIN32);
          unsigned grp = (unsigned)((__ballot(cond) >> gb) & 0xFFFFull);
          unsigned rng = ((1u << lend) - 1) & ~((1u << l) - 1);
          grp &= rng;
          mm = grp ? (__ffs(grp) - 1) : lend;
        }
        if (mm < lend) { if (row == mm) ek = 0.0; }
        double p = __shfl(dk, gb + l);
        if (mm == l) { ++l; if (l <= lend) continue; else break; }
        if (mm == l + 1) {
          double rt1, rt2, c, s;
          dlaev2_d(__shfl(dk, gb + l), __shfl(ek, gb + l),
                   __shfl(dk, gb + l + 1), rt1, rt2, c, s);
          {
            double a = Zs[base + row][base + l], b = Zs[base + row][base + l + 1];
            Zs[base + row][base + l] = c * a + s * b;
            Zs[base + row][base + l + 1] = -s * a + c * b;
          }
          if (row == l) { dk = rt1; ek = 0.0; }
          if (row == l + 1) dk = rt2;
          l += 2; if (l <= lend) continue; else break;
        }
        if (jtot == nmaxit) break;
        ++jtot;
        double el = __shfl(ek, gb + l);
        double g = (__shfl(dk, gb + l + 1) - p) / (2.0 * el);
        double r = sqrt(g * g + 1.0);
        g = __shfl(dk, gb + mm) - p + el / (g + lapsign(r, g));
        double s = 1.0, c = 1.0; p = 0.0;
        double carry = 0.0;
        bool first = true;
        for (int i = mm - 1; i >= l; --i) {
          double za = Zs[base + row][base + i];  // fresh col i
          double ei = __shfl(ek, gb + i);
          double f = s * ei, b = c * ei;
          dlartg_d(g, f, c, s, r);
          if (i != mm - 1) { if (row == i + 1) ek = r; }
          g = __shfl(dk, gb + i + 1) - p;
          r = (__shfl(dk, gb + i) - g) * s + 2.0 * c * b;
          p = s * r;
          if (row == i + 1) dk = g + p;
          g = c * r - b;
          // fused rot (stored cw=c, sw=-s): col i+1 final, col i carries
          double zb = first ? Zs[base + row][base + i + 1] : carry;
          Zs[base + row][base + i + 1] = s * za + c * zb;
          carry = c * za - s * zb;
          first = false;
        }
        Zs[base + row][base + l] = carry;
        if (row == l) { dk -= p; ek = g; }
      }
    } else {  // ---- QR ----
      for (;;) {
        int mm;
        {
          int lm1 = (row == 0) ? 0 : row - 1;
          double dkm1 = __shfl(dk, gb + lm1);
          double ekm1 = __shfl(ek, gb + lm1);
          bool cond = (ekm1 * ekm1 <= (eps2 * fabs(dk)) * fabs(dkm1) + SAFMIN32);
          unsigned grp = (unsigned)((__ballot(cond) >> gb) & 0xFFFFull);
          unsigned rng = ((1u << (l + 1)) - 1) & ~((1u << (lend + 1)) - 1);
          grp &= rng;
          mm = grp ? (31 - __clz(grp)) : lend;
        }
        if (mm > lend) { if (row == mm - 1) ek = 0.0; }
        double p = __shfl(dk, gb + l);
        if (mm == l) { --l; if (l >= lend) continue; else break; }
        if (mm == l - 1) {
          double rt1, rt2, c, s;
          dlaev2_d(__shfl(dk, gb + l - 1), __shfl(ek, gb + l - 1),
                   __shfl(dk, gb + l), rt1, rt2, c, s);
          {
            double a = Zs[base + row][base + l - 1], b = Zs[base + row][base + l];
            Zs[base + row][base + l - 1] = c * a + s * b;
            Zs[base + row][base + l] = -s * a + c * b;
          }
          if (row == l - 1) { dk = rt1; ek = 0.0; }
          if (row == l) dk = rt2;
          l -= 2; if (l >= lend) continue; else break;
        }
        if (jtot == nmaxit) break;
        ++jtot;
        double elm1 = __shfl(ek, gb + l - 1);
        double g = (__shfl(dk, gb + l - 1) - p) / (2.0 * elm1);
        double r = sqrt(g * g + 1.0);
        g = __shfl(dk, gb + mm) - p + elm1 / (g + lapsign(r, g));
        double s = 1.0, c = 1.0; p = 0.0;
        double carry = 0.0;
        bool first = true;
        for (int i = mm; i <= l - 1; ++i) {
          double zb = Zs[base + row][base + i + 1];  // fresh col i+1
          double ei = __shfl(ek, gb + i);
          double f = s * ei, b = c * ei;
          dlartg_d(g, f, c, s, r);
          if (i != mm) { if (row == i - 1) ek = r; }
          g = __shfl(dk, gb + i) - p;
          r = (__shfl(dk, gb + i + 1) - g) * s + 2.0 * c * b;
          p = s * r;
          if (row == i) dk = g + p;
          g = c * r - b;
          // fused rot (stored cw=c, sw=+s): col i final, col i+1 carries
          double za = first ? Zs[base + row][base + i] : carry;
          Zs[base + row][base + i] = c * za + s * zb;
          carry = -s * za + c * zb;
          first = false;
        }
        Zs[base + row][base + l] = carry;
        if (row == l) dk -= p;
        if (row == l - 1) ek = g;
      }
    }
  }
  // final selection sort ascending (first-index-of-min, strict <, as LAPACK)
  for (int ii = 1; ii < n; ++ii) {
    int i = ii - 1;
    double p = __shfl(dk, gb + i);
    double mv = (row >= ii) ? dk : 1.0e300;
    mv = fmin(mv, __shfl_xor(mv, 8));
    mv = fmin(mv, __shfl_xor(mv, 4));
    mv = fmin(mv, __shfl_xor(mv, 2));
    mv = fmin(mv, __shfl_xor(mv, 1));
    if (mv < p) {
      unsigned grp = (unsigned)((__ballot(row >= ii && dk == mv) >> gb) & 0xFFFFull);
      int k = __ffs(grp) - 1;
      double dko = __shfl(dk, gb + k);
      if (row == k) dk = p;
      if (row == i) dk = dko;
      double t = Zs[base + row][base + i];
      Zs[base + row][base + i] = Zs[base + row][base + k];
      Zs[base + row][base + k] = t;
    }
  }
}

// ------------- D&C merge with faithful DLAED2 deflation (dlaed1/2/3) -------
// (R1 version, verbatim.)
static __device__ void merge_dc(int off, int n, double rho_in, int lane,
                                double (*Zs)[65], double (*Zn)[65], float* ScF,
                                double* dd, double* dlam, double* wz,
                                double* zt, double* lamv, double* zloc,
                                double* dloc, double* lamfin, double* dvalS,
                                double* rz2, int* indx, int* slist, int* dlist,
                                int* dcolS) {
  const int N1 = n / 2;
  if (lane < n) {
    int r = (lane < N1) ? (off + N1 - 1) : (off + N1);
    double z = Zs[r][off + lane];
    if (rho_in < 0.0 && lane >= N1) z = -z;
    zloc[lane] = z * 0.70710678118654752440;
    dloc[lane] = dd[off + lane];
  }
  __syncthreads();
  const double rho = fabs(2.0 * rho_in);
  // stable DLAMRG merge order
  if (lane < n) {
    double a = dloc[lane];
    int pos;
    if (lane < N1) {
      int c2 = 0;
      for (int i = N1; i < n; ++i) c2 += (dloc[i] < a) ? 1 : 0;
      pos = lane + c2;
    } else {
      int c1 = 0;
      for (int i = 0; i < N1; ++i) c1 += (dloc[i] <= a) ? 1 : 0;
      pos = (lane - N1) + c1;
    }
    indx[pos] = lane;
  }
  __syncthreads();
  double mx = (lane < n) ? fmax(fabs(dloc[lane]), fabs(zloc[lane])) : 0.0;
  mx = wred_max(mx);
  const double tol = 8.0 * EPS32 * mx;
  __syncthreads();

  // ---- DLAED2 deflation scan (wave-uniform; rotations row-parallel) ----
  int K = 0, nD = 0;
  {
    int pj = -1, j = 0;
    for (; j < n; ++j) {
      int cj = indx[j];
      if (rho * fabs(zloc[cj]) <= tol) { dlist[nD] = cj; ++nD; }
      else { pj = cj; ++j; break; }
    }
    if (pj >= 0) {
      for (; j < n; ++j) {
        int nj = indx[j];
        if (rho * fabs(zloc[nj]) <= tol) { dlist[nD] = nj; ++nD; continue; }
        double s0 = zloc[pj], c0 = zloc[nj];
        double ta = sqrt(c0 * c0 + s0 * s0);  // DLAPY2 (values O(1))
        double tt = dloc[nj] - dloc[pj];
        double cc = c0 / ta, ss = -s0 / ta;
        if (fabs(tt * cc * ss) <= tol) {
          // type-2 deflation: DROT(Q(:,pj), Q(:,nj), cc, ss)
          zloc[nj] = ta; zloc[pj] = 0.0;
          {
            double a = Zs[lane][off + pj], b = Zs[lane][off + nj];
            Zs[lane][off + pj] = cc * a + ss * b;
            Zs[lane][off + nj] = cc * b - ss * a;
          }
          double ndp = dloc[pj] * cc * cc + dloc[nj] * ss * ss;
          dloc[nj] = dloc[pj] * ss * ss + dloc[nj] * cc * cc;
          dloc[pj] = ndp;
          dlist[nD] = pj; ++nD;
          pj = nj;
        } else {
          slist[K] = pj; ++K;
          pj = nj;
        }
      }
      slist[K] = pj; ++K;
    }
  }
  __syncthreads();
  // sort deflated by (updated) d ascending (stable)
  if (lane == 0) {
    for (int m = 0; m < nD; ++m) { dvalS[m] = dloc[dlist[m]]; dcolS[m] = dlist[m]; }
    for (int a = 1; a < nD; ++a) {
      double v = dvalS[a]; int ci = dcolS[a]; int b = a - 1;
      while (b >= 0 && dvalS[b] > v) { dvalS[b+1] = dvalS[b]; dcolS[b+1] = dcolS[b]; --b; }
      dvalS[b+1] = v; dcolS[b+1] = ci;
    }
  }
  __syncthreads();
  if (lane < K) {
    const double dv = dloc[slist[lane]], zv = zloc[slist[lane]];
    dlam[lane] = dv; wz[lane] = zv; rz2[lane] = rho * (zv * zv);
  }
  __syncthreads();

  // ---- secular roots (dlaed4-style, tau relative to nearest pole) ----
  if (lane < K) {
    int jl = lane, pjp; double lo, hi;
    double sumz2 = 0.0;
    for (int i = 0; i < K; ++i) sumz2 += wz[i] * wz[i];
    if (jl < K - 1) {
      double mid = 0.5 * (dlam[jl] + dlam[jl + 1]);
      double f = 1.0;
      for (int i = 0; i < K; ++i) f += rho * wz[i] * wz[i] / (dlam[i] - mid);
      double gaph = 0.5 * (dlam[jl + 1] - dlam[jl]);
      if (f > 0.0) { pjp = jl;     lo = 0.0;   hi = gaph; }
      else         { pjp = jl + 1; lo = -gaph; hi = 0.0;  }
    } else { pjp = K - 1; lo = 0.0; hi = rho * sumz2; }
    double sig = dlam[pjp];
    double tau = 0.5 * (lo + hi);
    for (int it = 0; it < 100; ++it) {
      double g = 1.0, gp = 0.0;
      for (int i = 0; i < K; ++i) {
        double inv = 1.0 / ((dlam[i] - sig) - tau);
        double q = rz2[i] * inv;
        g += q;
        gp += q * inv;
      }
      if (g > 0.0) hi = tau; else lo = tau;
      double tn = tau - g / gp;
      if (!(tn > lo && tn < hi)) tn = 0.5 * (lo + hi);
      double df = fabs(tn - tau);
      tau = tn;
      if (df <= 1.0e-12 * (fabs(tau) + 1e-30)) break;
    }
    lamv[jl] = sig + tau;
    for (int i = 0; i < K; ++i)
      ScF[i * 65 + jl] = (float)((dlam[i] - sig) - tau);
  }
  __syncthreads();
  // ---- dlaed3 z-tilde: sign(ztilde)=sign(w) ----
  if (lane < K) {
    int i = lane;
    double wv = (double)ScF[i * 65 + i];
    for (int j2 = 0; j2 < K; ++j2) {
      if (j2 == i) continue;
      wv *= (double)ScF[i * 65 + j2] / (dlam[i] - dlam[j2]);
    }
    double mag = sqrt(fmax(-wv, 0.0));
    zt[i] = (wz[i] >= 0.0) ? mag : -mag;
  }
  __syncthreads();
  // ---- secular vectors (normalized positively) ----
  if (lane < K) {
    double nrm2 = 0.0;
    for (int i = 0; i < K; ++i) {
      double sv = zt[i] / (double)ScF[i * 65 + lane];
      ScF[i * 65 + lane] = (float)sv;
      nrm2 += sv * sv;
    }
    float inv = (float)(1.0 / sqrt(nrm2));
    for (int i = 0; i < K; ++i) ScF[i * 65 + lane] *= inv;
  }
  __syncthreads();
  // ---- build new columns into Zn at final (merged ascending) positions ----
  if (lane < K) {
    int cnt = 0;
    for (int m = 0; m < nD; ++m) cnt += (dvalS[m] < lamv[lane]) ? 1 : 0;
    int fp = lane + cnt;
    for (int c0 = 0; c0 < n; c0 += 16) {
      double res[16];
#pragma unroll
      for (int t = 0; t < 16; ++t) res[t] = 0.0;
      for (int i = 0; i < K; ++i) {
        double sv = (double)ScF[i * 65 + lane];
        int col = off + slist[i];
#pragma unroll
        for (int t = 0; t < 16; ++t) res[t] += Zs[off + c0 + t][col] * sv;
      }
#pragma unroll
      for (int t = 0; t < 16; ++t) Zn[c0 + t][fp] = res[t];
    }
    lamfin[fp] = lamv[lane];
  }
  __syncthreads();
  for (int m = 0; m < nD; ++m) {
    int cnt = 0;
    for (int jl = 0; jl < K; ++jl) cnt += (lamv[jl] <= dvalS[m]) ? 1 : 0;
    int fp = m + cnt;
    if (lane < n) Zn[lane][fp] = Zs[off + lane][off + dcolS[m]];
    if (lane == 0) lamfin[fp] = dvalS[m];
  }
  __syncthreads();
  if (lane < n) {
    for (int c = 0; c < n; ++c) Zs[off + lane][off + c] = Zn[lane][c];
    dd[off + lane] = f32r(lamfin[lane]);  // f32 level boundary
  }
  __syncthreads();
}

// ---------------- Kernel 2: eigensolver + oracle + output ------------------
// (R1 structure: 64 threads, 1 wave; only the base-solve call changed.)
__global__ __launch_bounds__(64, 1) void eig_kernel(float* __restrict__ gbuf) {
  const int bh = blockIdx.x, b = bh >> 4, h = bh & 15;
  const int lane = threadIdx.x;
  float* G = gbuf + (size_t)bh * 4096;

  __shared__ double Zs[64][65];
  __shared__ double Zn[64][65];
  __shared__ double varch[64][64];
  __shared__ double ScD[2080];
  __shared__ double dd[64], ee[64], tauv[64], varr[64], wv[64];
  __shared__ double dlam[64], wz[64], zt[64], lamv[64], zloc[64], dloc[64];
  __shared__ double lamfin[64], dvalS[64], dsave[64], esave[64], rz2[64];
  __shared__ int indx[64], slist[64], dlist[64], dcolS[64];
  float* ScF = (float*)ScD;

  // ---- load gram into LDS (f64) ----
  double (*Zw)[65] = Zs;
  for (int r = 0; r < 64; ++r) Zw[r][lane] = (double)G[r * 64 + lane];
  __syncthreads();

  // ---- Householder tridiagonalization (dsytd2, UPLO='L') ----
  for (int i = 0; i < 63; ++i) {
    double xv = (lane >= i + 2) ? Zw[i][lane] : 0.0;
    double xn2 = wred_sum(xv * xv);
    double alpha = Zw[i][i + 1];
    double beta, taui;
    if (xn2 == 0.0) { taui = 0.0; beta = alpha; }
    else {
      double nrm = sqrt(alpha * alpha + xn2);
      beta = (alpha >= 0.0) ? -nrm : nrm;
      taui = (beta - alpha) / beta;
    }
    if (lane == 0) { dd[i] = Zw[i][i]; ee[i] = beta; tauv[i] = taui; }
    if (taui != 0.0) {
      double vl = (lane == i + 1) ? 1.0
                                  : ((lane >= i + 2) ? xv / (alpha - beta) : 0.0);
      varr[lane] = vl;
      if (lane >= i + 1) varch[i][lane] = vl;
      __syncthreads();
      double wr = 0.0;
      for (int c = i + 1; c < 64; ++c) wr += Zw[c][lane] * varr[c];
      wr *= taui;
      double wtv = wred_sum((lane >= i + 1) ? wr * vl : 0.0);
      wr -= 0.5 * taui * wtv * vl;
      wv[lane] = (lane >= i + 1) ? wr : 0.0;
      __syncthreads();
      if (lane >= i + 1) {
        double vc = vl, wc = wr;
        for (int r = i + 1; r < 64; ++r)
          Zw[r][lane] -= (varr[r] * wc + wv[r] * vc);
      }
      __syncthreads();
    } else {
      __syncthreads();
    }
  }
  if (lane == 0) dd[63] = Zw[63][63];
  __syncthreads();

  // ---- emulate f32 ssytrd output, sstedc scaling, dlaed0 corrections ----
  dd[lane] = f32r(dd[lane]);
  if (lane < 63) ee[lane] = f32r(ee[lane]);
  __syncthreads();
  double mx = fabs(dd[lane]);
  if (lane < 63) mx = fmax(mx, fabs(ee[lane]));
  const double orgnrm = wred_max(mx);
  dd[lane] = f32r(dd[lane] / orgnrm);
  if (lane < 63) ee[lane] = f32r(ee[lane] / orgnrm);
  __syncthreads();
  dsave[lane] = dd[lane];
  esave[lane] = (lane < 63) ? ee[lane] : 0.0;
  __syncthreads();
  if (lane == 0) {
    const int ms[3] = {15, 31, 47};
    for (int a = 0; a < 3; ++a) {
      double ae = fabs(ee[ms[a]]);
      dd[ms[a]] = f32r(dd[ms[a]] - ae);
      dd[ms[a] + 1] = f32r(dd[ms[a] + 1] - ae);
    }
  }
  __syncthreads();

  // ---- base solves: DSTEQR on 4 x 16 blocks, register d/e per group ----
  for (int r = 0; r < 64; ++r) Zs[r][lane] = (r == lane) ? 1.0 : 0.0;
  __syncthreads();
  {
    const int bb = lane >> 4, row16 = lane & 15;
    double dk = dd[bb * 16 + row16];
    double ek = (row16 < 15) ? ee[bb * 16 + row16] : 0.0;
    dsteqr16_grp(Zs, bb * 16, lane, dk, ek);
    dd[bb * 16 + row16] = dk;
  }
  __syncthreads();
  dd[lane] = f32r(dd[lane]);  // f32 level boundary
  __syncthreads();

  // ---- merges: (16+16)A, (16+16)B, then 32+32 ----
  merge_dc(0, 32, ee[15], lane, Zs, Zn, ScF, dd, dlam, wz, zt, lamv, zloc,
           dloc, lamfin, dvalS, rz2, indx, slist, dlist, dcolS);
  merge_dc(32, 32, ee[47], lane, Zs, Zn, ScF, dd, dlam, wz, zt, lamv, zloc,
           dloc, lamfin, dvalS, rz2, indx, slist, dlist, dcolS);
  merge_dc(0, 64, ee[31], lane, Zs, Zn, ScF, dd, dlam, wz, zt, lamv, zloc,
           dloc, lamfin, dvalS, rz2, indx, slist, dlist, dcolS);

  // ---- ORACLE: ||T Z - Z L||oo on the scaled tridiagonal ----
  double tres = 0.0;
  {
    const double lam = dd[lane];
    for (int i = 0; i < 64; ++i) {
      double tv = dsave[i] * Zs[i][lane];
      if (i > 0) tv += esave[i - 1] * Zs[i - 1][lane];
      if (i < 63) tv += esave[i] * Zs[i + 1][lane];
      tres = fmax(tres, fabs(tv - lam * Zs[i][lane]));
    }
  }
  tres = wred_max(tres);
  const bool dc_bad = !(tres <= 2e-5);  // NaN-safe; f32-accurate pipeline

  // ---- back-transform: Z <- H(0) ... H(62) Z ----
  for (int i = 62; i >= 0; --i) {
    double ti = tauv[i];
    if (ti != 0.0) {
      varr[lane] = varch[i][lane];
      __syncthreads();
      double wc = 0.0;
      for (int r = i + 1; r < 64; ++r) wc += varr[r] * Zs[r][lane];
      wc *= ti;
      for (int r = i + 1; r < 64; ++r) Zs[r][lane] -= varr[r] * wc;
      __syncthreads();
    }
  }
  __syncthreads();

  const double sentinel = dc_bad ? 1.0e6 : 0.0;
  // ---- output: out[b, h*64+i, j] = w_j * V[j][i] / 8 ----
  const double wj = dd[lane] * orgnrm * 0.125;
  for (int i2 = 0; i2 < 64; ++i2) {
    G[i2 * 64 + lane] = (float)(wj * Zs[lane][i2] + sentinel);
  }
}

extern "C" void kernel_launch(void* const* d_in, const int* in_sizes, int n_in,
                              void* d_out, int out_size, void* d_ws,
                              size_t ws_size, hipStream_t stream) {
  (void)in_sizes; (void)n_in; (void)out_size; (void)d_ws; (void)ws_size;
  const float* x = (const float*)d_in[0];
  float* out = (float*)d_out;
  gram_kernel<<<dim3(NMAT), dim3(256), 0, stream>>>(x, out);
  eig_kernel<<<dim3(NMAT), dim3(64), 0, stream>>>(out);
}

// Round 6
// 1650.542 us; speedup vs baseline: 1.7378x; 1.0197x over previous
//
#include <hip/hip_runtime.h>
#include <math.h>

// PCA_75307956568420: 128 x (64x64 symmetric eigenproblem) whose eigenvector
// SIGNS must match LAPACK ssyevd on the f32 gram. Full SSTEDC replication:
// Householder tridiag (dsytd2 'L') -> dstedc scale -> dlaed0 splits (16x4) ->
// DSTEQR base solves (QL/QR, dlartg/dlaev2 conventions) -> dlaed1/2/3 merges
// WITH faithful dlaed2 deflation -> back-transform. f32-rounding at every
// level boundary keeps decision comparisons within ~1ulp of the reference.
//
// R6 = R5 + wave-level concurrency (arithmetic preserved exactly):
//  - eig: 256 threads / 4 waves. DSTEQR: wave w solves block w using R5's
//    exonerated dsteqr16_grp VERBATIM (each wave's 4 groups hold identical
//    block-w data; redundant LDS ops are lockstep-idempotent). Removes the
//    x4 divergence serialization of the bulge-sweep f64 chains.
//  - merges A (cols 0-31) and B (cols 32-63) run CONCURRENTLY on waves 0/1.
//    merge_dc unchanged except Zn indexing made off-based (3 lines; off=0
//    paths bit-identical to R5); scratch pointers offset by +32 for B.
//    Waves not in a merge execute a 12-barrier stub (merge_dc has exactly
//    12 unconditional __syncthreads -- keep in sync!).
//  - tridiag / scale / back-transform: w0-only, internal barriers replaced
//    by wave-local WSYNC (same single-wave arithmetic as R5).
//  - load / oracle / output split across 4 waves (disjoint rows; oracle
//    combined via fmax -- order-independent).
// Per-wave __syncthreads count fixed at 32 (uniform, unconditional).

#define NMAT 128
#define EPS32 5.9604644775390625e-8
#define SAFMIN32 1.1754943508222875e-38
#define MERGE_BARRIERS 12

#define WSYNC() do { asm volatile("s_waitcnt lgkmcnt(0)" ::: "memory"); \
                     __builtin_amdgcn_sched_barrier(0); } while (0)

static __device__ __forceinline__ double f32r(double x) { return (double)(float)x; }
static __device__ __forceinline__ double lapsign(double a, double b) {
  return (b >= 0.0) ? fabs(a) : -fabs(a);
}

__device__ __forceinline__ double wred_sum(double v) {
#pragma unroll
  for (int o = 32; o > 0; o >>= 1) v += __shfl_xor(v, o, 64);
  return v;
}
__device__ __forceinline__ double wred_max(double v) {
#pragma unroll
  for (int o = 32; o > 0; o >>= 1) v = fmax(v, __shfl_xor(v, o, 64));
  return v;
}

// ------- Kernel 1: column stats + normalized Gram (f64 acc, f32 out) -------
// (R2 version, unchanged: 256 threads, 4x4 acc/thread, dbuf pipeline.)
__global__ __launch_bounds__(256) void gram_kernel(const float* __restrict__ x,
                                                   float* __restrict__ gbuf) {
  const int bh = blockIdx.x, b = bh >> 4, h = bh & 15;
  const float* base = x + (size_t)b * 4096 * 1024 + h * 64;
  __shared__ double rs1[16][64];
  __shared__ double rs2[16][64];
  __shared__ int rsc[16][64];
  __shared__ float sm[64], si[64];
  __shared__ double tiled[2][64][68];
  const int tid = threadIdx.x, q = tid & 15, r0 = tid >> 4, lane = tid & 63;

  double s1[4] = {0.0, 0.0, 0.0, 0.0}, s2[4] = {0.0, 0.0, 0.0, 0.0};
  int cc[4] = {0, 0, 0, 0};
#pragma unroll 4
  for (int s = r0; s < 4096; s += 16) {
    const float4 v = *(const float4*)&base[(size_t)s * 1024 + 4 * q];
    const float vs[4] = {v.x, v.y, v.z, v.w};
#pragma unroll
    for (int k = 0; k < 4; ++k) {
      const double dv = (double)vs[k];
      s1[k] += dv;
      s2[k] += dv * dv;
      cc[k] += (vs[k] != 0.0f) ? 1 : 0;
    }
  }
#pragma unroll
  for (int k = 0; k < 4; ++k) {
    rs1[r0][4 * q + k] = s1[k];
    rs2[r0][4 * q + k] = s2[k];
    rsc[r0][4 * q + k] = cc[k];
  }
  __syncthreads();
  if (tid < 64) {
    double S1 = 0.0, S2 = 0.0;
    int C = 0;
    for (int a = 0; a < 16; ++a) { S1 += rs1[a][tid]; S2 += rs2[a][tid]; C += rsc[a][tid]; }
    const double m = (C > 0) ? S1 / (double)C : 0.0;
    double var = (C > 0) ? (S2 - 2.0 * m * S1 + 4096.0 * m * m) / (double)C : 0.0;
    var = fmax(var, 0.0);
    const double sd = sqrt(var);
    sm[tid] = (float)m;
    si[tid] = (sd > 0.0) ? (float)(1.0 / sd) : 0.0f;
  }
  __syncthreads();

  const float4 mj4 = *(const float4*)&sm[4 * q];
  const float4 iv4 = *(const float4*)&si[4 * q];

  auto stash = [&](int buf, const float4& v, int sl) {
    const bool nz4 = (v.x != 0.0f) || (v.y != 0.0f) || (v.z != 0.0f) || (v.w != 0.0f);
    const unsigned long long mb = __ballot(nz4);
    const unsigned rowm = (unsigned)(mb >> (lane & 48)) & 0xFFFFu;
    double* tr = &tiled[buf][sl][4 * q];
    if (rowm) {
      tr[0] = (double)((v.x - mj4.x) * iv4.x);
      tr[1] = (double)((v.y - mj4.y) * iv4.y);
      tr[2] = (double)((v.z - mj4.z) * iv4.z);
      tr[3] = (double)((v.w - mj4.w) * iv4.w);
    } else {
      tr[0] = 0.0; tr[1] = 0.0; tr[2] = 0.0; tr[3] = 0.0;
    }
  };

  double acc[4][4];
#pragma unroll
  for (int r = 0; r < 4; ++r)
#pragma unroll
    for (int c = 0; c < 4; ++c) acc[r][c] = 0.0;

  {
    const float4 p0 = *(const float4*)&base[(size_t)(r0) * 1024 + 4 * q];
    const float4 p1 = *(const float4*)&base[(size_t)(r0 + 16) * 1024 + 4 * q];
    const float4 p2 = *(const float4*)&base[(size_t)(r0 + 32) * 1024 + 4 * q];
    const float4 p3 = *(const float4*)&base[(size_t)(r0 + 48) * 1024 + 4 * q];
    stash(0, p0, r0); stash(0, p1, r0 + 16); stash(0, p2, r0 + 32); stash(0, p3, r0 + 48);
  }
  __syncthreads();

  for (int t = 0; t < 64; ++t) {
    const int cur = t & 1;
    float4 n0, n1, n2, n3;
    const bool more = (t + 1 < 64);
    if (more) {
      const size_t sb = (size_t)(t + 1) * 64;
      n0 = *(const float4*)&base[(sb + r0) * 1024 + 4 * q];
      n1 = *(const float4*)&base[(sb + r0 + 16) * 1024 + 4 * q];
      n2 = *(const float4*)&base[(sb + r0 + 32) * 1024 + 4 * q];
      n3 = *(const float4*)&base[(sb + r0 + 48) * 1024 + 4 * q];
    }
    for (int ss = 0; ss < 64; ++ss) {
      const double* ta = &tiled[cur][ss][4 * r0];
      const double* tb = &tiled[cur][ss][4 * q];
      const double a0 = ta[0], a1 = ta[1], a2 = ta[2], a3 = ta[3];
      const double b0 = tb[0], b1 = tb[1], b2 = tb[2], b3 = tb[3];
      acc[0][0] += a0 * b0; acc[0][1] += a0 * b1; acc[0][2] += a0 * b2; acc[0][3] += a0 * b3;
      acc[1][0] += a1 * b0; acc[1][1] += a1 * b1; acc[1][2] += a1 * b2; acc[1][3] += a1 * b3;
      acc[2][0] += a2 * b0; acc[2][1] += a2 * b1; acc[2][2] += a2 * b2; acc[2][3] += a2 * b3;
      acc[3][0] += a3 * b0; acc[3][1] += a3 * b1; acc[3][2] += a3 * b2; acc[3][3] += a3 * b3;
    }
    if (more) {
      stash(cur ^ 1, n0, r0); stash(cur ^ 1, n1, r0 + 16);
      stash(cur ^ 1, n2, r0 + 32); stash(cur ^ 1, n3, r0 + 48);
    }
    __syncthreads();
  }

  float* G = gbuf + (size_t)bh * 4096;
#pragma unroll
  for (int r = 0; r < 4; ++r)
#pragma unroll
    for (int c = 0; c < 4; ++c)
      G[(4 * r0 + r) * 64 + 4 * q + c] = (float)acc[r][c];
}

// ----------------------------- DLARTG / DLAEV2 -----------------------------
static __device__ void dlartg_d(double f, double g, double& cs, double& sn,
                                double& r) {
  if (g == 0.0) { cs = 1.0; sn = 0.0; r = f; }
  else if (f == 0.0) { cs = 0.0; sn = 1.0; r = g; }
  else {
    r = sqrt(f * f + g * g);
    cs = f / r; sn = g / r;
    if (fabs(f) > fabs(g) && cs < 0.0) { cs = -cs; sn = -sn; r = -r; }
  }
}

static __device__ void dlaev2_d(double a, double b, double c, double& rt1,
                                double& rt2, double& cs1, double& sn1) {
  double sm = a + c, df = a - c, adf = fabs(df), tb = b + b, ab = fabs(tb);
  double acmx, acmn;
  if (fabs(a) > fabs(c)) { acmx = a; acmn = c; } else { acmx = c; acmn = a; }
  double rt;
  if (adf > ab) rt = adf * sqrt(1.0 + (ab / adf) * (ab / adf));
  else if (adf < ab) rt = ab * sqrt(1.0 + (adf / ab) * (adf / ab));
  else rt = ab * sqrt(2.0);
  int sgn1;
  if (sm < 0.0) {
    rt1 = 0.5 * (sm - rt); sgn1 = -1;
    rt2 = (acmx / rt1) * acmn - (b / rt1) * b;
  } else if (sm > 0.0) {
    rt1 = 0.5 * (sm + rt); sgn1 = 1;
    rt2 = (acmx / rt1) * acmn - (b / rt1) * b;
  } else { rt1 = 0.5 * rt; rt2 = -0.5 * rt; sgn1 = 1; }
  int sgn2; double cs;
  if (df >= 0.0) { cs = df + rt; sgn2 = 1; } else { cs = df - rt; sgn2 = -1; }
  double acs = fabs(cs);
  if (acs > ab) {
    double ct = -tb / cs;
    sn1 = 1.0 / sqrt(1.0 + ct * ct); cs1 = ct * sn1;
  } else {
    if (ab == 0.0) { cs1 = 1.0; sn1 = 0.0; }
    else {
      double tn = -cs / tb;
      cs1 = 1.0 / sqrt(1.0 + tn * tn); sn1 = tn * cs1;
    }
  }
  if (sgn1 == sgn2) { double tn = cs1; cs1 = -sn1; sn1 = tn; }
}

// ------------- DSTEQR (n=16, COMPZ='I'), group-local registers -------------
// (R5 version, VERBATIM.) Each 16-lane group solves the block whose data it
// holds. In R6, wave w feeds all 4 of its groups block-w data -> redundant
// lockstep execution (idempotent LDS ops), waves run concurrently.
static __device__ void dsteqr16_grp(double (*Zs)[65], int base, int lane,
                                    double& dk, double& ek) {
  const int n = 16, nm1 = 15;
  const double eps = EPS32, eps2 = EPS32 * EPS32;
  const int gb = lane & 48;   // group base lane
  const int row = lane & 15;  // group-local index; also Z-row owner
  int l1 = 0, jtot = 0, nmaxit = n * 30;
  while (l1 < n) {
    if (l1 > 0) { if (row == l1 - 1) ek = 0.0; }
    int m;
    {
      double dkp1 = __shfl(dk, gb + ((row + 1) & 15));
      bool cond = (fabs(ek) <= (sqrt(fabs(dk)) * sqrt(fabs(dkp1))) * eps);
      unsigned grp = (unsigned)((__ballot(cond) >> gb) & 0xFFFFull);
      grp &= 0x7FFFu & ~((1u << l1) - 1);
      m = grp ? (__ffs(grp) - 1) : nm1;
      if (m < nm1) { if (row == m) ek = 0.0; }
    }
    int l = l1, lend = m;
    l1 = m + 1;
    if (lend == l) continue;
    if (fabs(__shfl(dk, gb + lend)) < fabs(__shfl(dk, gb + l))) {
      int t = l; l = lend; lend = t;
    }
    if (lend > l) {  // ---- QL ----
      for (;;) {
        int mm;
        {
          double dkp1 = __shfl(dk, gb + ((row + 1) & 15));
          bool cond = (ek * ek <= (eps2 * fabs(dk)) * fabs(dkp1) + SAFMIN32);
          unsigned grp = (unsigned)((__ballot(cond) >> gb) & 0xFFFFull);
          unsigned rng = ((1u << lend) - 1) & ~((1u << l) - 1);
          grp &= rng;
          mm = grp ? (__ffs(grp) - 1) : lend;
        }
        if (mm < lend) { if (row == mm) ek = 0.0; }
        double p = __shfl(dk, gb + l);
        if (mm == l) { ++l; if (l <= lend) continue; else break; }
        if (mm == l + 1) {
          double rt1, rt2, c, s;
          dlaev2_d(__shfl(dk, gb + l), __shfl(ek, gb + l),
                   __shfl(dk, gb + l + 1), rt1, rt2, c, s);
          {
            double a = Zs[base + row][base + l], b = Zs[base + row][base + l + 1];
            Zs[base + row][base + l] = c * a + s * b;
            Zs[base + row][base + l + 1] = -s * a + c * b;
          }
          if (row == l) { dk = rt1; ek = 0.0; }
          if (row == l + 1) dk = rt2;
          l += 2; if (l <= lend) continue; else break;
        }
        if (jtot == nmaxit) break;
        ++jtot;
        double el = __shfl(ek, gb + l);
        double g = (__shfl(dk, gb + l + 1) - p) / (2.0 * el);
        double r = sqrt(g * g + 1.0);
        g = __shfl(dk, gb + mm) - p + el / (g + lapsign(r, g));
        double s = 1.0, c = 1.0; p = 0.0;
        double carry = 0.0;
        bool first = true;
        for (int i = mm - 1; i >= l; --i) {
          double za = Zs[base + row][base + i];  // fresh col i
          double ei = __shfl(ek, gb + i);
          double f = s * ei, b = c * ei;
          dlartg_d(g, f, c, s, r);
          if (i != mm - 1) { if (row == i + 1) ek = r; }
          g = __shfl(dk, gb + i + 1) - p;
          r = (__shfl(dk, gb + i) - g) * s + 2.0 * c * b;
          p = s * r;
          if (row == i + 1) dk = g + p;
          g = c * r - b;
          // fused rot (stored cw=c, sw=-s): col i+1 final, col i carries
          double zb = first ? Zs[base + row][base + i + 1] : carry;
          Zs[base + row][base + i + 1] = s * za + c * zb;
          carry = c * za - s * zb;
          first = false;
        }
        Zs[base + row][base + l] = carry;
        if (row == l) { dk -= p; ek = g; }
      }
    } else {  // ---- QR ----
      for (;;) {
        int mm;
        {
          int lm1 = (row == 0) ? 0 : row - 1;
          double dkm1 = __shfl(dk, gb + lm1);
          double ekm1 = __shfl(ek, gb + lm1);
          bool cond = (ekm1 * ekm1 <= (eps2 * fabs(dk)) * fabs(dkm1) + SAFMIN32);
          unsigned grp = (unsigned)((__ballot(cond) >> gb) & 0xFFFFull);
          unsigned rng = ((1u << (l + 1)) - 1) & ~((1u << (lend + 1)) - 1);
          grp &= rng;
          mm = grp ? (31 - __clz(grp)) : lend;
        }
        if (mm > lend) { if (row == mm - 1) ek = 0.0; }
        double p = __shfl(dk, gb + l);
        if (mm == l) { --l; if (l >= lend) continue; else break; }
        if (mm == l - 1) {
          double rt1, rt2, c, s;
          dlaev2_d(__shfl(dk, gb + l - 1), __shfl(ek, gb + l - 1),
                   __shfl(dk, gb + l), rt1, rt2, c, s);
          {
            double a = Zs[base + row][base + l - 1], b = Zs[base + row][base + l];
            Zs[base + row][base + l - 1] = c * a + s * b;
            Zs[base + row][base + l] = -s * a + c * b;
          }
          if (row == l - 1) { dk = rt1; ek = 0.0; }
          if (row == l) dk = rt2;
          l -= 2; if (l >= lend) continue; else break;
        }
        if (jtot == nmaxit) break;
        ++jtot;
        double elm1 = __shfl(ek, gb + l - 1);
        double g = (__shfl(dk, gb + l - 1) - p) / (2.0 * elm1);
        double r = sqrt(g * g + 1.0);
        g = __shfl(dk, gb + mm) - p + elm1 / (g + lapsign(r, g));
        double s = 1.0, c = 1.0; p = 0.0;
        double carry = 0.0;
        bool first = true;
        for (int i = mm; i <= l - 1; ++i) {
          double zb = Zs[base + row][base + i + 1];  // fresh col i+1
          double ei = __shfl(ek, gb + i);
          double f = s * ei, b = c * ei;
          dlartg_d(g, f, c, s, r);
          if (i != mm) { if (row == i - 1) ek = r; }
          g = __shfl(dk, gb + i) - p;
          r = (__shfl(dk, gb + i + 1) - g) * s + 2.0 * c * b;
          p = s * r;
          if (row == i) dk = g + p;
          g = c * r - b;
          // fused rot (stored cw=c, sw=+s): col i final, col i+1 carries
          double za = first ? Zs[base + row][base + i] : carry;
          Zs[base + row][base + i] = c * za + s * zb;
          carry = -s * za + c * zb;
          first = false;
        }
        Zs[base + row][base + l] = carry;
        if (row == l) dk -= p;
        if (row == l - 1) ek = g;
      }
    }
  }
  // final selection sort ascending (first-index-of-min, strict <, as LAPACK)
  for (int ii = 1; ii < n; ++ii) {
    int i = ii - 1;
    double p = __shfl(dk, gb + i);
    double mv = (row >= ii) ? dk : 1.0e300;
    mv = fmin(mv, __shfl_xor(mv, 8));
    mv = fmin(mv, __shfl_xor(mv, 4));
    mv = fmin(mv, __shfl_xor(mv, 2));
    mv = fmin(mv, __shfl_xor(mv, 1));
    if (mv < p) {
      unsigned grp = (unsigned)((__ballot(row >= ii && dk == mv) >> gb) & 0xFFFFull);
      int k = __ffs(grp) - 1;
      double dko = __shfl(dk, gb + k);
      if (row == k) dk = p;
      if (row == i) dk = dko;
      double t = Zs[base + row][base + i];
      Zs[base + row][base + i] = Zs[base + row][base + k];
      Zs[base + row][base + k] = t;
    }
  }
}

// ------------- D&C merge with faithful DLAED2 deflation (dlaed1/2/3) -------
// (R5 version; ONLY change: Zn indexing is off-based so merges at off=0 and
// off=32 touch disjoint Zn regions. off=0 paths bit-identical to R5.)
// Contains exactly MERGE_BARRIERS (12) unconditional __syncthreads().
static __device__ void merge_dc(int off, int n, double rho_in, int lane,
                                double (*Zs)[65], double (*Zn)[65], float* ScF,
                                double* dd, double* dlam, double* wz,
                                double* zt, double* lamv, double* zloc,
                                double* dloc, double* lamfin, double* dvalS,
                                double* rz2, int* indx, int* slist, int* dlist,
                                int* dcolS) {
  const int N1 = n / 2;
  if (lane < n) {
    int r = (lane < N1) ? (off + N1 - 1) : (off + N1);
    double z = Zs[r][off + lane];
    if (rho_in < 0.0 && lane >= N1) z = -z;
    zloc[lane] = z * 0.70710678118654752440;
    dloc[lane] = dd[off + lane];
  }
  __syncthreads();  // 1
  const double rho = fabs(2.0 * rho_in);
  // stable DLAMRG merge order
  if (lane < n) {
    double a = dloc[lane];
    int pos;
    if (lane < N1) {
      int c2 = 0;
      for (int i = N1; i < n; ++i) c2 += (dloc[i] < a) ? 1 : 0;
      pos = lane + c2;
    } else {
      int c1 = 0;
      for (int i = 0; i < N1; ++i) c1 += (dloc[i] <= a) ? 1 : 0;
      pos = (lane - N1) + c1;
    }
    indx[pos] = lane;
  }
  __syncthreads();  // 2
  double mx = (lane < n) ? fmax(fabs(dloc[lane]), fabs(zloc[lane])) : 0.0;
  mx = wred_max(mx);
  const double tol = 8.0 * EPS32 * mx;
  __syncthreads();  // 3

  // ---- DLAED2 deflation scan (wave-uniform; rotations row-parallel) ----
  int K = 0, nD = 0;
  {
    int pj = -1, j = 0;
    for (; j < n; ++j) {
      int cj = indx[j];
      if (rho * fabs(zloc[cj]) <= tol) { dlist[nD] = cj; ++nD; }
      else { pj = cj; ++j; break; }
    }
    if (pj >= 0) {
      for (; j < n; ++j) {
        int nj = indx[j];
        if (rho * fabs(zloc[nj]) <= tol) { dlist[nD] = nj; ++nD; continue; }
        double s0 = zloc[pj], c0 = zloc[nj];
        double ta = sqrt(c0 * c0 + s0 * s0);  // DLAPY2 (values O(1))
        double tt = dloc[nj] - dloc[pj];
        double cc = c0 / ta, ss = -s0 / ta;
        if (fabs(tt * cc * ss) <= tol) {
          // type-2 deflation: DROT(Q(:,pj), Q(:,nj), cc, ss)
          zloc[nj] = ta; zloc[pj] = 0.0;
          {
            double a = Zs[lane][off + pj], b = Zs[lane][off + nj];
            Zs[lane][off + pj] = cc * a + ss * b;
            Zs[lane][off + nj] = cc * b - ss * a;
          }
          double ndp = dloc[pj] * cc * cc + dloc[nj] * ss * ss;
          dloc[nj] = dloc[pj] * ss * ss + dloc[nj] * cc * cc;
          dloc[pj] = ndp;
          dlist[nD] = pj; ++nD;
          pj = nj;
        } else {
          slist[K] = pj; ++K;
          pj = nj;
        }
      }
      slist[K] = pj; ++K;
    }
  }
  __syncthreads();  // 4
  // sort deflated by (updated) d ascending (stable)
  if (lane == 0) {
    for (int m = 0; m < nD; ++m) { dvalS[m] = dloc[dlist[m]]; dcolS[m] = dlist[m]; }
    for (int a = 1; a < nD; ++a) {
      double v = dvalS[a]; int ci = dcolS[a]; int b = a - 1;
      while (b >= 0 && dvalS[b] > v) { dvalS[b+1] = dvalS[b]; dcolS[b+1] = dcolS[b]; --b; }
      dvalS[b+1] = v; dcolS[b+1] = ci;
    }
  }
  __syncthreads();  // 5
  if (lane < K) {
    const double dv = dloc[slist[lane]], zv = zloc[slist[lane]];
    dlam[lane] = dv; wz[lane] = zv; rz2[lane] = rho * (zv * zv);
  }
  __syncthreads();  // 6

  // ---- secular roots (dlaed4-style, tau relative to nearest pole) ----
  if (lane < K) {
    int jl = lane, pjp; double lo, hi;
    double sumz2 = 0.0;
    for (int i = 0; i < K; ++i) sumz2 += wz[i] * wz[i];
    if (jl < K - 1) {
      double mid = 0.5 * (dlam[jl] + dlam[jl + 1]);
      double f = 1.0;
      for (int i = 0; i < K; ++i) f += rho * wz[i] * wz[i] / (dlam[i] - mid);
      double gaph = 0.5 * (dlam[jl + 1] - dlam[jl]);
      if (f > 0.0) { pjp = jl;     lo = 0.0;   hi = gaph; }
      else         { pjp = jl + 1; lo = -gaph; hi = 0.0;  }
    } else { pjp = K - 1; lo = 0.0; hi = rho * sumz2; }
    double sig = dlam[pjp];
    double tau = 0.5 * (lo + hi);
    for (int it = 0; it < 100; ++it) {
      double g = 1.0, gp = 0.0;
      for (int i = 0; i < K; ++i) {
        double inv = 1.0 / ((dlam[i] - sig) - tau);
        double q = rz2[i] * inv;
        g += q;
        gp += q * inv;
      }
      if (g > 0.0) hi = tau; else lo = tau;
      double tn = tau - g / gp;
      if (!(tn > lo && tn < hi)) tn = 0.5 * (lo + hi);
      double df = fabs(tn - tau);
      tau = tn;
      if (df <= 1.0e-12 * (fabs(tau) + 1e-30)) break;
    }
    lamv[jl] = sig + tau;
    for (int i = 0; i < K; ++i)
      ScF[i * 65 + jl] = (float)((dlam[i] - sig) - tau);
  }
  __syncthreads();  // 7
  // ---- dlaed3 z-tilde: sign(ztilde)=sign(w) ----
  if (lane < K) {
    int i = lane;
    double wv = (double)ScF[i * 65 + i];
    for (int j2 = 0; j2 < K; ++j2) {
      if (j2 == i) continue;
      wv *= (double)ScF[i * 65 + j2] / (dlam[i] - dlam[j2]);
    }
    double mag = sqrt(fmax(-wv, 0.0));
    zt[i] = (wz[i] >= 0.0) ? mag : -mag;
  }
  __syncthreads();  // 8
  // ---- secular vectors (normalized positively) ----
  if (lane < K) {
    double nrm2 = 0.0;
    for (int i = 0; i < K; ++i) {
      double sv = zt[i] / (double)ScF[i * 65 + lane];
      ScF[i * 65 + lane] = (float)sv;
      nrm2 += sv * sv;
    }
    float inv = (float)(1.0 / sqrt(nrm2));
    for (int i = 0; i < K; ++i) ScF[i * 65 + lane] *= inv;
  }
  __syncthreads();  // 9
  // ---- build new columns into Zn at final (merged ascending) positions ----
  if (lane < K) {
    int cnt = 0;
    for (int m = 0; m < nD; ++m) cnt += (dvalS[m] < lamv[lane]) ? 1 : 0;
    int fp = lane + cnt;
    for (int c0 = 0; c0 < n; c0 += 16) {
      double res[16];
#pragma unroll
      for (int t = 0; t < 16; ++t) res[t] = 0.0;
      for (int i = 0; i < K; ++i) {
        double sv = (double)ScF[i * 65 + lane];
        int col = off + slist[i];
#pragma unroll
        for (int t = 0; t < 16; ++t) res[t] += Zs[off + c0 + t][col] * sv;
      }
#pragma unroll
      for (int t = 0; t < 16; ++t) Zn[off + c0 + t][off + fp] = res[t];
    }
    lamfin[fp] = lamv[lane];
  }
  __syncthreads();  // 10
  for (int m = 0; m < nD; ++m) {
    int cnt = 0;
    for (int jl = 0; jl < K; ++jl) cnt += (lamv[jl] <= dvalS[m]) ? 1 : 0;
    int fp = m + cnt;
    if (lane < n) Zn[off + lane][off + fp] = Zs[off + lane][off + dcolS[m]];
    if (lane == 0) lamfin[fp] = dvalS[m];
  }
  __syncthreads();  // 11
  if (lane < n) {
    for (int c = 0; c < n; ++c) Zs[off + lane][off + c] = Zn[off + lane][off + c];
    dd[off + lane] = f32r(lamfin[lane]);  // f32 level boundary
  }
  __syncthreads();  // 12
}

// stub for waves not participating in a merge: must match merge_dc's
// internal barrier count exactly.
static __device__ __forceinline__ void merge_stub() {
#pragma unroll
  for (int k = 0; k < MERGE_BARRIERS; ++k) __syncthreads();
}

// ---------------- Kernel 2: eigensolver + oracle + output ------------------
// 256 threads / 4 waves. Per-wave __syncthreads count = 32 (uniform).
__global__ __launch_bounds__(256, 1) void eig_kernel(float* __restrict__ gbuf) {
  const int bh = blockIdx.x;
  const int tid = threadIdx.x, lane = tid & 63, w = tid >> 6;
  float* G = gbuf + (size_t)bh * 4096;

  __shared__ double Zs[64][65];
  __shared__ double Zn[64][65];
  __shared__ double varch[64][64];
  __shared__ double ScD[2080];
  __shared__ double dd[64], ee[64], tauv[64], varr[64], wv[64];
  __shared__ double dlam[64], wz[64], zt[64], lamv[64], zloc[64], dloc[64];
  __shared__ double lamfin[64], dvalS[64], dsave[64], esave[64], rz2[64];
  __shared__ double pbuf[4][64];
  __shared__ double s_org;
  __shared__ int indx[64], slist[64], dlist[64], dcolS[64];
  float* ScF = (float*)ScD;

  // ---- load gram into LDS (f64), 16 rows per wave ----
  double (*Zw)[65] = Zs;
  for (int r = 16 * w; r < 16 * w + 16; ++r) Zw[r][lane] = (double)G[r * 64 + lane];
  __syncthreads();  // B1

  // ---- Householder tridiagonalization (dsytd2, UPLO='L'), wave 0 only ----
  // (R5 arithmetic verbatim; barriers -> wave-local WSYNC.)
  if (w == 0) {
    for (int i = 0; i < 63; ++i) {
      double xv = (lane >= i + 2) ? Zw[i][lane] : 0.0;
      double xn2 = wred_sum(xv * xv);
      double alpha = Zw[i][i + 1];
      double beta, taui;
      if (xn2 == 0.0) { taui = 0.0; beta = alpha; }
      else {
        double nrm = sqrt(alpha * alpha + xn2);
        beta = (alpha >= 0.0) ? -nrm : nrm;
        taui = (beta - alpha) / beta;
      }
      if (lane == 0) { dd[i] = Zw[i][i]; ee[i] = beta; tauv[i] = taui; }
      if (taui != 0.0) {
        double vl = (lane == i + 1) ? 1.0
                                    : ((lane >= i + 2) ? xv / (alpha - beta) : 0.0);
        varr[lane] = vl;
        if (lane >= i + 1) varch[i][lane] = vl;
        WSYNC();
        double wr = 0.0;
        for (int c = i + 1; c < 64; ++c) wr += Zw[c][lane] * varr[c];
        wr *= taui;
        double wtv = wred_sum((lane >= i + 1) ? wr * vl : 0.0);
        wr -= 0.5 * taui * wtv * vl;
        wv[lane] = (lane >= i + 1) ? wr : 0.0;
        WSYNC();
        if (lane >= i + 1) {
          double vc = vl, wc = wr;
          for (int r = i + 1; r < 64; ++r)
            Zw[r][lane] -= (varr[r] * wc + wv[r] * vc);
        }
        WSYNC();
      }
    }
    if (lane == 0) dd[63] = Zw[63][63];
  }
  __syncthreads();  // B2

  // ---- emulate f32 ssytrd output, sstedc scaling, dlaed0 corrections ----
  if (w == 0) {
    dd[lane] = f32r(dd[lane]);
    if (lane < 63) ee[lane] = f32r(ee[lane]);
    double mx = fabs(dd[lane]);
    if (lane < 63) mx = fmax(mx, fabs(ee[lane]));
    const double orgnrm = wred_max(mx);
    if (lane == 0) s_org = orgnrm;
    dd[lane] = f32r(dd[lane] / orgnrm);
    if (lane < 63) ee[lane] = f32r(ee[lane] / orgnrm);
    dsave[lane] = dd[lane];
    esave[lane] = (lane < 63) ? ee[lane] : 0.0;
    WSYNC();
    if (lane == 0) {
      const int ms[3] = {15, 31, 47};
      for (int a = 0; a < 3; ++a) {
        double ae = fabs(ee[ms[a]]);
        dd[ms[a]] = f32r(dd[ms[a]] - ae);
        dd[ms[a] + 1] = f32r(dd[ms[a] + 1] - ae);
      }
    }
  }
  __syncthreads();  // B3

  // ---- base solves: wave w solves block w (4 redundant groups/wave) ----
  for (int r = 16 * w; r < 16 * w + 16; ++r) Zs[r][lane] = (r == lane) ? 1.0 : 0.0;
  __syncthreads();  // B4
  {
    const int row16 = lane & 15;
    double dk = dd[16 * w + row16];
    double ek = (row16 < 15) ? ee[16 * w + row16] : 0.0;
    dsteqr16_grp(Zs, 16 * w, lane, dk, ek);
    dd[16 * w + row16] = dk;  // 4 lanes write the same value
  }
  __syncthreads();  // B5
  if (w == 0) dd[lane] = f32r(dd[lane]);  // f32 level boundary
  __syncthreads();  // B6

  // ---- merges: (16+16)A on wave0 CONCURRENT with (16+16)B on wave1 ----
  if (w == 0) {
    merge_dc(0, 32, ee[15], lane, Zs, Zn, ScF, dd, dlam, wz, zt, lamv, zloc,
             dloc, lamfin, dvalS, rz2, indx, slist, dlist, dcolS);
  } else if (w == 1) {
    merge_dc(32, 32, ee[47], lane, Zs, Zn, ScF + 32 * 65, dd, dlam + 32,
             wz + 32, zt + 32, lamv + 32, zloc + 32, dloc + 32, lamfin + 32,
             dvalS + 32, rz2 + 32, indx + 32, slist + 32, dlist + 32,
             dcolS + 32);
  } else {
    merge_stub();
  }  // 12 barriers each path
  // ---- 32+32 merge on wave 0 ----
  if (w == 0) {
    merge_dc(0, 64, ee[31], lane, Zs, Zn, ScF, dd, dlam, wz, zt, lamv, zloc,
             dloc, lamfin, dvalS, rz2, indx, slist, dlist, dcolS);
  } else {
    merge_stub();
  }  // 12 barriers each path

  // ---- ORACLE: ||T Z - Z L||oo on the scaled tridiagonal, 4-wave split ----
  {
    double tresp = 0.0;
    const double lam = dd[lane];
    for (int i = 16 * w; i < 16 * w + 16; ++i) {
      double tv = dsave[i] * Zs[i][lane];
      if (i > 0) tv += esave[i - 1] * Zs[i - 1][lane];
      if (i < 63) tv += esave[i] * Zs[i + 1][lane];
      tresp = fmax(tresp, fabs(tv - lam * Zs[i][lane]));
    }
    pbuf[w][lane] = tresp;
  }
  __syncthreads();  // B7
  double tres = fmax(fmax(pbuf[0][lane], pbuf[1][lane]),
                     fmax(pbuf[2][lane], pbuf[3][lane]));
  tres = wred_max(tres);
  const bool dc_bad = !(tres <= 2e-5);  // NaN-safe; f32-accurate pipeline

  // ---- back-transform: Z <- H(0) ... H(62) Z, wave 0 only ----
  if (w == 0) {
    for (int i = 62; i >= 0; --i) {
      double ti = tauv[i];
      if (ti != 0.0) {
        varr[lane] = varch[i][lane];
        WSYNC();
        double wc = 0.0;
        for (int r = i + 1; r < 64; ++r) wc += varr[r] * Zs[r][lane];
        wc *= ti;
        for (int r = i + 1; r < 64; ++r) Zs[r][lane] -= varr[r] * wc;
        WSYNC();
      }
    }
  }
  __syncthreads();  // B8

  const double sentinel = dc_bad ? 1.0e6 : 0.0;
  // ---- output: out[b, h*64+i, j] = w_j * V[j][i] / 8, 4-wave split ----
  const double wj = dd[lane] * s_org * 0.125;
  for (int i2 = 16 * w; i2 < 16 * w + 16; ++i2) {
    G[i2 * 64 + lane] = (float)(wj * Zs[lane][i2] + sentinel);
  }
}

extern "C" void kernel_launch(void* const* d_in, const int* in_sizes, int n_in,
                              void* d_out, int out_size, void* d_ws,
                              size_t ws_size, hipStream_t stream) {
  (void)in_sizes; (void)n_in; (void)out_size; (void)d_ws; (void)ws_size;
  const float* x = (const float*)d_in[0];
  float* out = (float*)d_out;
  gram_kernel<<<dim3(NMAT), dim3(256), 0, stream>>>(x, out);
  eig_kernel<<<dim3(NMAT), dim3(256), 0, stream>>>(out);
}